// Round 2
// baseline (2039.953 us; speedup 1.0000x reference)
//
#include <hip/hip_runtime.h>
#include <hip/hip_bf16.h>

typedef __hip_bfloat16 bf16;
typedef __bf16 bf16x8 __attribute__((ext_vector_type(8)));
typedef float f32x4 __attribute__((ext_vector_type(4)));

static constexpr int Bq = 4, Tq = 2048, Dq = 1024;

__device__ inline float b2f(bf16 h) { return __bfloat162float(h); }
__device__ inline bf16 f2b(float f) { return __float2bfloat16(f); }

__device__ inline float ldf(const float* p, int i) { return p[i]; }
__device__ inline float ldf(const bf16* p, int i) { return b2f(p[i]); }

// ---------------- LayerNorm (one block per row, D=1024), fp32 gamma/beta ----------------
template <typename Tin>
__global__ void ln_kernel(const Tin* __restrict__ x, const float* __restrict__ g,
                          const float* __restrict__ b, bf16* __restrict__ out, int d)
{
    const int row = blockIdx.x;
    const int tid = threadIdx.x;
    const Tin* xr = x + (size_t)row * d;
    bf16* orow = out + (size_t)row * d;
    float v[8];
    float sum = 0.f, sq = 0.f;
    int c = 0;
    for (int s = tid; s < d; s += 256, ++c) {
        float f = ldf(xr, s);
        v[c] = f; sum += f; sq += f * f;
    }
    for (int o = 32; o > 0; o >>= 1) { sum += __shfl_xor(sum, o); sq += __shfl_xor(sq, o); }
    __shared__ float ssum[4], ssq[4];
    const int w = tid >> 6;
    if ((tid & 63) == 0) { ssum[w] = sum; ssq[w] = sq; }
    __syncthreads();
    const float ts = ssum[0] + ssum[1] + ssum[2] + ssum[3];
    const float tq = ssq[0] + ssq[1] + ssq[2] + ssq[3];
    const float mean = ts / d;
    const float var = tq / d - mean * mean;
    const float rs = rsqrtf(var + 1e-5f);
    c = 0;
    for (int s = tid; s < d; s += 256, ++c) {
        float y = (v[c] - mean) * rs * g[s] + b[s];
        orow[s] = f2b(y);
    }
}

// ---------------- Tiled transpose fp32 -> bf16: out[c][r] = (bf16)in[r][c] ----------------
// grid: (cols/32, rows/32), block: (32, 8)
__global__ void transpose_f2b_kernel(const float* __restrict__ in, bf16* __restrict__ out,
                                     long ldin, long ldout)
{
    __shared__ float tile[32][33];
    const int c0 = blockIdx.x * 32, r0 = blockIdx.y * 32;
    const int tx = threadIdx.x, ty = threadIdx.y;
    for (int i = 0; i < 4; ++i) {
        int r = r0 + ty + i * 8;
        tile[ty + i * 8][tx] = in[(size_t)r * ldin + c0 + tx];
    }
    __syncthreads();
    for (int i = 0; i < 4; ++i) {
        int cc = ty + i * 8;
        out[(size_t)(c0 + cc) * ldout + r0 + tx] = f2b(tile[tx][cc]);
    }
}

// ---------------- Tiled transpose bf16 -> bf16 (for V^T) ----------------
__global__ void transpose_b2b_kernel(const bf16* __restrict__ in, bf16* __restrict__ out,
                                     long ldin, long ldout, long inBatch, long outBatch)
{
    __shared__ bf16 tile[32][33];
    const bf16* ip = in + (size_t)blockIdx.z * inBatch;
    bf16* op = out + (size_t)blockIdx.z * outBatch;
    const int c0 = blockIdx.x * 32, r0 = blockIdx.y * 32;
    const int tx = threadIdx.x, ty = threadIdx.y;
    for (int i = 0; i < 4; ++i) {
        int r = r0 + ty + i * 8;
        tile[ty + i * 8][tx] = ip[(size_t)r * ldin + c0 + tx];
    }
    __syncthreads();
    for (int i = 0; i < 4; ++i) {
        int cc = ty + i * 8;
        op[(size_t)(c0 + cc) * ldout + r0 + tx] = tile[tx][cc];
    }
}

// ---------------- Causal softmax over rows of attn[b][t][:] (in-place, bf16) ----------------
__global__ void softmax_kernel(bf16* __restrict__ attn)
{
    const int row = blockIdx.x;           // 0..B*T-1
    const int bb = row >> 11;             // / T
    const int t = row & (Tq - 1);
    bf16* base = attn + (size_t)bb * Tq * Tq + (size_t)t * Tq;
    const int tid = threadIdx.x;
    const int len = t + 1;
    float ev[8];
    int c = 0;
    for (int s = tid; s < len; s += 256, ++c) ev[c] = b2f(base[s]);
    const int cnt = c;
    float mx = -1e30f;
    for (int i = 0; i < cnt; ++i) mx = fmaxf(mx, ev[i]);
    for (int o = 32; o > 0; o >>= 1) mx = fmaxf(mx, __shfl_xor(mx, o));
    __shared__ float sred[4];
    const int w = tid >> 6;
    if ((tid & 63) == 0) sred[w] = mx;
    __syncthreads();
    mx = fmaxf(fmaxf(sred[0], sred[1]), fmaxf(sred[2], sred[3]));
    __syncthreads();
    float sum = 0.f;
    for (int i = 0; i < cnt; ++i) { ev[i] = __expf(ev[i] - mx); sum += ev[i]; }
    for (int o = 32; o > 0; o >>= 1) sum += __shfl_xor(sum, o);
    if ((tid & 63) == 0) sred[w] = sum;
    __syncthreads();
    const float inv = 1.f / (sred[0] + sred[1] + sred[2] + sred[3]);
    c = 0;
    for (int s = tid; s < Tq; s += 256) {
        float p = (s < len) ? ev[c++] * inv : 0.f;
        base[s] = f2b(p);
    }
}

// ---------------- GEMM C = act(scale * A @ Bt^T + bias) ----------------
// A: [M,K] bf16 row-major (lda), Bt: [N,K] bf16 row-major (ldb).
// Output: bf16 (Cb) or fp32 (Cf) — exactly one non-null. bias fp32 (per-col).
// Block tile 64x64, 4 waves 2x2, each wave 2x2 MFMA 16x16x32 tiles, frags direct from global.
// Verified layouts (m89/m91): A/B frag elem j = op[l15][quad*8+j]; C/D: row=quad*4+reg, col=l15.
__global__ void gemm_nt(const bf16* __restrict__ A, const bf16* __restrict__ Bt,
                        const float* __restrict__ bias,
                        bf16* __restrict__ Cb, float* __restrict__ Cf,
                        int K, long lda, long ldb, long ldc,
                        long sA, long sB, long sC,
                        float scale, int act, int causal)
{
    const int m0 = blockIdx.y * 64, n0 = blockIdx.x * 64;
    if (causal && n0 > m0 + 63) return;   // fully-masked tile; softmax writes the zeros
    const bf16* Ab = A + (size_t)blockIdx.z * sA;
    const bf16* Bb = Bt + (size_t)blockIdx.z * sB;
    const int tid = threadIdx.x;
    const int wid = tid >> 6, lane = tid & 63;
    const int wr = wid >> 1, wc = wid & 1;
    const int l15 = lane & 15, quad = lane >> 4;

    const bf16* ap0 = Ab + (size_t)(m0 + wr * 32 + l15) * lda + quad * 8;
    const bf16* ap1 = ap0 + 16 * lda;
    const bf16* bp0 = Bb + (size_t)(n0 + wc * 32 + l15) * ldb + quad * 8;
    const bf16* bp1 = bp0 + 16 * ldb;

    f32x4 acc00 = {0.f, 0.f, 0.f, 0.f};
    f32x4 acc01 = acc00, acc10 = acc00, acc11 = acc00;

    for (int k = 0; k < K; k += 32) {
        bf16x8 a0 = *reinterpret_cast<const bf16x8*>(ap0 + k);
        bf16x8 a1 = *reinterpret_cast<const bf16x8*>(ap1 + k);
        bf16x8 b0 = *reinterpret_cast<const bf16x8*>(bp0 + k);
        bf16x8 b1 = *reinterpret_cast<const bf16x8*>(bp1 + k);
        acc00 = __builtin_amdgcn_mfma_f32_16x16x32_bf16(a0, b0, acc00, 0, 0, 0);
        acc01 = __builtin_amdgcn_mfma_f32_16x16x32_bf16(a0, b1, acc01, 0, 0, 0);
        acc10 = __builtin_amdgcn_mfma_f32_16x16x32_bf16(a1, b0, acc10, 0, 0, 0);
        acc11 = __builtin_amdgcn_mfma_f32_16x16x32_bf16(a1, b1, acc11, 0, 0, 0);
    }

    #pragma unroll
    for (int ij = 0; ij < 4; ++ij) {
        const int i = ij >> 1, j = ij & 1;
        f32x4 acc = (ij == 0) ? acc00 : (ij == 1) ? acc01 : (ij == 2) ? acc10 : acc11;
        const int row = m0 + wr * 32 + i * 16 + quad * 4;
        const int col = n0 + wc * 32 + j * 16 + l15;
        const float bv = bias ? bias[col] : 0.f;
        #pragma unroll
        for (int r = 0; r < 4; ++r) {
            float vv = scale * acc[r] + bv;
            if (act == 1) {  // tanh-approx GELU
                float x3 = vv * vv * vv;
                vv = 0.5f * vv * (1.f + tanhf(0.7978845608028654f * (vv + 0.044715f * x3)));
            }
            const size_t idx = (size_t)(row + r) * ldc + col + (size_t)blockIdx.z * sC;
            if (Cf) Cf[idx] = vv;
            else    Cb[idx] = f2b(vv);
        }
    }
}

extern "C" void kernel_launch(void* const* d_in, const int* in_sizes, int n_in,
                              void* d_out, int out_size, void* d_ws, size_t ws_size,
                              hipStream_t stream)
{
    (void)in_sizes; (void)n_in; (void)out_size; (void)ws_size;
    const float* x     = (const float*)d_in[0];
    const float* ln1g  = (const float*)d_in[1];
    const float* ln1b  = (const float*)d_in[2];
    const float* Wqkv  = (const float*)d_in[3];
    const float* bqkv  = (const float*)d_in[4];
    const float* Wproj = (const float*)d_in[5];
    const float* bproj = (const float*)d_in[6];
    const float* ln2g  = (const float*)d_in[7];
    const float* ln2b  = (const float*)d_in[8];
    const float* W1    = (const float*)d_in[9];
    const float* b1    = (const float*)d_in[10];
    const float* W2    = (const float*)d_in[11];
    const float* b2    = (const float*)d_in[12];
    float* out = (float*)d_out;

    // ---- workspace arena (bf16 elements) ----
    char* ws = (char*)d_ws;
    size_t off = 0;
    auto alloc = [&](size_t elems) { bf16* p = (bf16*)(ws + off); off += elems * sizeof(bf16); return p; };
    bf16* WqkvT  = alloc(3072UL * 1024);        //  6.3 MB
    bf16* WprojT = alloc(1024UL * 1024);        //  2.1 MB
    bf16* W1T    = alloc(4096UL * 1024);        //  8.4 MB
    bf16* W2T    = alloc(1024UL * 4096);        //  8.4 MB
    bf16* h      = alloc(8192UL * 1024);        // 16.8 MB  LN1 out; later reused as `a`
    bf16* kqv    = alloc(8192UL * 3072);        // 50.3 MB  (per-row k|q|v interleave)
    bf16* vT     = alloc(4UL * 1024 * 2048);    // 16.8 MB  V^T per batch
    bf16* attn   = alloc(4UL * 2048 * 2048);    // 33.6 MB  scores -> probs (in place)
    // raw-memory aliases (lifetimes disjoint):
    bf16* a   = h;                      // attn@V out (h dead after QKV GEMM)
    bf16* p   = kqv;                    // proj out (kqv fully dead after scores + vT)
    bf16* h2  = kqv + 8192UL * 1024;    // LN2 out
    bf16* m   = kqv + 2UL * 8192 * 1024;// MLP hidden 8192x4096 = 67.1 MB, spans kqv-tail+vT+attn

    const dim3 tb(32, 8);
    const long T3D = (long)Tq * 3072, TT = (long)Tq * Tq, DT = (long)Dq * Tq, TD = (long)Tq * Dq;

    // weight transposes + fp32->bf16 (W[K,N] -> WT[N,K])
    transpose_f2b_kernel<<<dim3(96, 32), tb, 0, stream>>>(Wqkv,  WqkvT,  3072L, 1024L);
    transpose_f2b_kernel<<<dim3(32, 32), tb, 0, stream>>>(Wproj, WprojT, 1024L, 1024L);
    transpose_f2b_kernel<<<dim3(128, 32), tb, 0, stream>>>(W1,   W1T,    4096L, 1024L);
    transpose_f2b_kernel<<<dim3(32, 128), tb, 0, stream>>>(W2,   W2T,    1024L, 4096L);

    // h = LN1(x)   (fp32 in, bf16 out)
    ln_kernel<float><<<8192, 256, 0, stream>>>(x, ln1g, ln1b, h, Dq);

    // kqv = h @ Wqkv + bqkv    [8192, 3072]   (split order per row: k | q | v)
    gemm_nt<<<dim3(48, 128, 1), 256, 0, stream>>>(h, WqkvT, bqkv, kqv, nullptr,
        1024, 1024L, 1024L, 3072L, 0L, 0L, 0L, 1.f, 0, 0);

    // vT[b][d][t] = v[b][t][d]
    transpose_b2b_kernel<<<dim3(32, 64, 4), tb, 0, stream>>>(kqv + 2048, vT, 3072L, 2048L, T3D, DT);

    // scores[b][t][s] = (q . k) / sqrt(T)   (skip fully-masked tiles)
    gemm_nt<<<dim3(32, 32, 4), 256, 0, stream>>>(kqv + 1024, kqv, nullptr, attn, nullptr,
        1024, 3072L, 3072L, 2048L, T3D, T3D, TT, 0.022097086912079608f, 0, 1);

    // causal softmax in place (writes zeros for s > t)
    softmax_kernel<<<8192, 256, 0, stream>>>(attn);

    // a = attn @ V
    gemm_nt<<<dim3(16, 32, 4), 256, 0, stream>>>(attn, vT, nullptr, a, nullptr,
        2048, 2048L, 2048L, 1024L, TT, DT, TD, 1.f, 0, 0);

    // p = a @ Wproj + bproj
    gemm_nt<<<dim3(16, 128, 1), 256, 0, stream>>>(a, WprojT, bproj, p, nullptr,
        1024, 1024L, 1024L, 1024L, 0L, 0L, 0L, 1.f, 0, 0);

    // h2 = LN2(p)   (bf16 in, bf16 out)
    ln_kernel<bf16><<<8192, 256, 0, stream>>>(p, ln2g, ln2b, h2, Dq);

    // m = gelu(h2 @ W1 + b1)   [8192, 4096]
    gemm_nt<<<dim3(64, 128, 1), 256, 0, stream>>>(h2, W1T, b1, m, nullptr,
        1024, 1024L, 1024L, 4096L, 0L, 0L, 0L, 1.f, 1, 0);

    // out = m @ W2 + b2        [8192, 1024]  (fp32 out)
    gemm_nt<<<dim3(16, 128, 1), 256, 0, stream>>>(m, W2T, b2, nullptr, out,
        4096, 4096L, 4096L, 1024L, 0L, 0L, 0L, 1.f, 0, 0);
}

// Round 3
// 617.146 us; speedup vs baseline: 3.3055x; 3.3055x over previous
//
#include <hip/hip_runtime.h>
#include <hip/hip_bf16.h>

typedef __hip_bfloat16 bf16;
typedef __bf16 bf16x8 __attribute__((ext_vector_type(8)));
typedef float f32x4 __attribute__((ext_vector_type(4)));

static constexpr int Bq = 4, Tq = 2048, Dq = 1024;

__device__ inline float b2f(bf16 h) { return __bfloat162float(h); }
__device__ inline bf16 f2b(float f) { return __float2bfloat16(f); }

__device__ inline float ldf(const float* p, int i) { return p[i]; }
__device__ inline float ldf(const bf16* p, int i) { return b2f(p[i]); }

// async global->LDS, 16 B per lane. LDS dst = wave-uniform base + lane*16.
__device__ __forceinline__ void gload_lds16(const bf16* g, bf16* lds_wave_base) {
    __builtin_amdgcn_global_load_lds((const __attribute__((address_space(1))) void*)g,
                                     (__attribute__((address_space(3))) void*)lds_wave_base,
                                     16, 0, 0);
}

// ---------------- LayerNorm (one block per row, D=1024), fp32 gamma/beta ----------------
template <typename Tin>
__global__ void ln_kernel(const Tin* __restrict__ x, const float* __restrict__ g,
                          const float* __restrict__ b, bf16* __restrict__ out, int d)
{
    const int row = blockIdx.x;
    const int tid = threadIdx.x;
    const Tin* xr = x + (size_t)row * d;
    bf16* orow = out + (size_t)row * d;
    float v[8];
    float sum = 0.f, sq = 0.f;
    int c = 0;
    for (int s = tid; s < d; s += 256, ++c) {
        float f = ldf(xr, s);
        v[c] = f; sum += f; sq += f * f;
    }
    for (int o = 32; o > 0; o >>= 1) { sum += __shfl_xor(sum, o); sq += __shfl_xor(sq, o); }
    __shared__ float ssum[4], ssq[4];
    const int w = tid >> 6;
    if ((tid & 63) == 0) { ssum[w] = sum; ssq[w] = sq; }
    __syncthreads();
    const float ts = ssum[0] + ssum[1] + ssum[2] + ssum[3];
    const float tq = ssq[0] + ssq[1] + ssq[2] + ssq[3];
    const float mean = ts / d;
    const float var = tq / d - mean * mean;
    const float rs = rsqrtf(var + 1e-5f);
    c = 0;
    for (int s = tid; s < d; s += 256, ++c) {
        float y = (v[c] - mean) * rs * g[s] + b[s];
        orow[s] = f2b(y);
    }
}

// ---------------- Tiled transpose fp32 -> bf16 ----------------
__global__ void transpose_f2b_kernel(const float* __restrict__ in, bf16* __restrict__ out,
                                     long ldin, long ldout)
{
    __shared__ float tile[32][33];
    const int c0 = blockIdx.x * 32, r0 = blockIdx.y * 32;
    const int tx = threadIdx.x, ty = threadIdx.y;
    for (int i = 0; i < 4; ++i) {
        int r = r0 + ty + i * 8;
        tile[ty + i * 8][tx] = in[(size_t)r * ldin + c0 + tx];
    }
    __syncthreads();
    for (int i = 0; i < 4; ++i) {
        int cc = ty + i * 8;
        out[(size_t)(c0 + cc) * ldout + r0 + tx] = f2b(tile[tx][cc]);
    }
}

// ---------------- Tiled transpose bf16 -> bf16 (for V^T) ----------------
__global__ void transpose_b2b_kernel(const bf16* __restrict__ in, bf16* __restrict__ out,
                                     long ldin, long ldout, long inBatch, long outBatch)
{
    __shared__ bf16 tile[32][33];
    const bf16* ip = in + (size_t)blockIdx.z * inBatch;
    bf16* op = out + (size_t)blockIdx.z * outBatch;
    const int c0 = blockIdx.x * 32, r0 = blockIdx.y * 32;
    const int tx = threadIdx.x, ty = threadIdx.y;
    for (int i = 0; i < 4; ++i) {
        int r = r0 + ty + i * 8;
        tile[ty + i * 8][tx] = ip[(size_t)r * ldin + c0 + tx];
    }
    __syncthreads();
    for (int i = 0; i < 4; ++i) {
        int cc = ty + i * 8;
        op[(size_t)(c0 + cc) * ldout + r0 + tx] = tile[tx][cc];
    }
}

// ---------------- Causal softmax over rows of attn[b][t][:] (in-place, bf16) ----------------
__global__ void softmax_kernel(bf16* __restrict__ attn)
{
    const int row = blockIdx.x;
    const int bb = row >> 11;
    const int t = row & (Tq - 1);
    bf16* base = attn + (size_t)bb * Tq * Tq + (size_t)t * Tq;
    const int tid = threadIdx.x;
    const int len = t + 1;
    float ev[8];
    int c = 0;
    for (int s = tid; s < len; s += 256, ++c) ev[c] = b2f(base[s]);
    const int cnt = c;
    float mx = -1e30f;
    for (int i = 0; i < cnt; ++i) mx = fmaxf(mx, ev[i]);
    for (int o = 32; o > 0; o >>= 1) mx = fmaxf(mx, __shfl_xor(mx, o));
    __shared__ float sred[4];
    const int w = tid >> 6;
    if ((tid & 63) == 0) sred[w] = mx;
    __syncthreads();
    mx = fmaxf(fmaxf(sred[0], sred[1]), fmaxf(sred[2], sred[3]));
    __syncthreads();
    float sum = 0.f;
    for (int i = 0; i < cnt; ++i) { ev[i] = __expf(ev[i] - mx); sum += ev[i]; }
    for (int o = 32; o > 0; o >>= 1) sum += __shfl_xor(sum, o);
    if ((tid & 63) == 0) sred[w] = sum;
    __syncthreads();
    const float inv = 1.f / (sred[0] + sred[1] + sred[2] + sred[3]);
    c = 0;
    for (int s = tid; s < Tq; s += 256) {
        float p = (s < len) ? ev[c++] * inv : 0.f;
        base[s] = f2b(p);
    }
}

// ---------------- 128x128 LDS-staged MFMA GEMM (m97 structure) ----------------
// C = act(scale * A @ Bt^T + bias). A:[M,K] (lda), Bt:[N,K] (ldb), bf16.
// 256 threads = 4 waves in 2x2; each wave owns a 64x64 quadrant = 4x4 MFMA tiles.
// LDS: A-tile 128x32 + B-tile 128x32 (lane-order contiguous; no padding - required
// by global_load_lds wave-uniform-base semantics). K-step 32.
__global__ void gemm128(const bf16* __restrict__ A, const bf16* __restrict__ Bt,
                        const float* __restrict__ bias,
                        bf16* __restrict__ Cb, float* __restrict__ Cf,
                        int K, long lda, long ldb, long ldc,
                        long sA, long sB, long sC,
                        float scale, int act, int causal)
{
    const int m0 = blockIdx.y * 128, n0 = blockIdx.x * 128;
    if (causal && n0 > m0 + 127) return;   // fully-masked tile; softmax writes the zeros

    __shared__ bf16 As[128 * 32];
    __shared__ bf16 Bs[128 * 32];

    const bf16* Ab = A + (size_t)blockIdx.z * sA;
    const bf16* Bb = Bt + (size_t)blockIdx.z * sB;
    const int tid = threadIdx.x;
    const int wid = tid >> 6, lane = tid & 63;
    const int wr = wid >> 1, wc = wid & 1;
    const int l15 = lane & 15, quad = lane >> 4;

    // staging addresses: issue 0 covers rows 0..63, issue 1 rows 64..127 of the tile.
    const int srow = wid * 16 + (lane >> 2);     // 0..63
    const int scol = (lane & 3) * 8;             // 0,8,16,24
    const bf16* agp0 = Ab + (size_t)(m0 + srow) * lda + scol;
    const bf16* agp1 = Ab + (size_t)(m0 + 64 + srow) * lda + scol;
    const bf16* bgp0 = Bb + (size_t)(n0 + srow) * ldb + scol;
    const bf16* bgp1 = Bb + (size_t)(n0 + 64 + srow) * ldb + scol;
    bf16* aw0 = As + wid * 512;                  // wave-uniform LDS bases (elements)
    bf16* aw1 = As + 2048 + wid * 512;
    bf16* bw0 = Bs + wid * 512;
    bf16* bw1 = Bs + 2048 + wid * 512;

    // fragment read offsets (elements)
    const int afo = (wr * 64 + l15) * 32 + quad * 8;
    const int bfo = (wc * 64 + l15) * 32 + quad * 8;

    f32x4 acc[4][4];
    #pragma unroll
    for (int i = 0; i < 4; ++i)
        #pragma unroll
        for (int j = 0; j < 4; ++j) acc[i][j] = (f32x4){0.f, 0.f, 0.f, 0.f};

    for (int k0 = 0; k0 < K; k0 += 32) {
        gload_lds16(agp0 + k0, aw0);
        gload_lds16(agp1 + k0, aw1);
        gload_lds16(bgp0 + k0, bw0);
        gload_lds16(bgp1 + k0, bw1);
        __syncthreads();   // drains vmcnt: LDS tile complete

        bf16x8 af[4], bf[4];
        #pragma unroll
        for (int i = 0; i < 4; ++i) af[i] = *reinterpret_cast<const bf16x8*>(As + afo + i * 512);
        #pragma unroll
        for (int j = 0; j < 4; ++j) bf[j] = *reinterpret_cast<const bf16x8*>(Bs + bfo + j * 512);
        #pragma unroll
        for (int i = 0; i < 4; ++i)
            #pragma unroll
            for (int j = 0; j < 4; ++j)
                acc[i][j] = __builtin_amdgcn_mfma_f32_16x16x32_bf16(af[i], bf[j], acc[i][j], 0, 0, 0);

        __syncthreads();   // protect LDS before next iteration overwrites
    }

    // epilogue: C/D layout row=quad*4+reg, col=l15 (m89/m91-verified)
    #pragma unroll
    for (int i = 0; i < 4; ++i) {
        const int row = m0 + wr * 64 + i * 16 + quad * 4;
        #pragma unroll
        for (int j = 0; j < 4; ++j) {
            const int col = n0 + wc * 64 + j * 16 + l15;
            const float bv = bias ? bias[col] : 0.f;
            #pragma unroll
            for (int r = 0; r < 4; ++r) {
                float vv = scale * acc[i][j][r] + bv;
                if (act == 1) {  // tanh-approx GELU
                    float x3 = vv * vv * vv;
                    vv = 0.5f * vv * (1.f + tanhf(0.7978845608028654f * (vv + 0.044715f * x3)));
                }
                const size_t idx = (size_t)(row + r) * ldc + col + (size_t)blockIdx.z * sC;
                if (Cf) Cf[idx] = vv;
                else    Cb[idx] = f2b(vv);
            }
        }
    }
}

extern "C" void kernel_launch(void* const* d_in, const int* in_sizes, int n_in,
                              void* d_out, int out_size, void* d_ws, size_t ws_size,
                              hipStream_t stream)
{
    (void)in_sizes; (void)n_in; (void)out_size; (void)ws_size;
    const float* x     = (const float*)d_in[0];
    const float* ln1g  = (const float*)d_in[1];
    const float* ln1b  = (const float*)d_in[2];
    const float* Wqkv  = (const float*)d_in[3];
    const float* bqkv  = (const float*)d_in[4];
    const float* Wproj = (const float*)d_in[5];
    const float* bproj = (const float*)d_in[6];
    const float* ln2g  = (const float*)d_in[7];
    const float* ln2b  = (const float*)d_in[8];
    const float* W1    = (const float*)d_in[9];
    const float* b1    = (const float*)d_in[10];
    const float* W2    = (const float*)d_in[11];
    const float* b2    = (const float*)d_in[12];
    float* out = (float*)d_out;

    // ---- workspace arena (bf16 elements) ----
    char* ws = (char*)d_ws;
    size_t off = 0;
    auto alloc = [&](size_t elems) { bf16* p = (bf16*)(ws + off); off += elems * sizeof(bf16); return p; };
    bf16* WqkvT  = alloc(3072UL * 1024);
    bf16* WprojT = alloc(1024UL * 1024);
    bf16* W1T    = alloc(4096UL * 1024);
    bf16* W2T    = alloc(1024UL * 4096);
    bf16* h      = alloc(8192UL * 1024);        // LN1 out; later reused as `a`
    bf16* kqv    = alloc(8192UL * 3072);        // per-row k|q|v
    bf16* vT     = alloc(4UL * 1024 * 2048);
    bf16* attn   = alloc(4UL * 2048 * 2048);
    // aliases (lifetimes disjoint):
    bf16* a   = h;
    bf16* p   = kqv;
    bf16* h2  = kqv + 8192UL * 1024;
    bf16* m   = kqv + 2UL * 8192 * 1024;        // spans kqv-tail + vT + attn

    const dim3 tb(32, 8);
    const long T3D = (long)Tq * 3072, TT = (long)Tq * Tq, DT = (long)Dq * Tq, TD = (long)Tq * Dq;

    transpose_f2b_kernel<<<dim3(96, 32), tb, 0, stream>>>(Wqkv,  WqkvT,  3072L, 1024L);
    transpose_f2b_kernel<<<dim3(32, 32), tb, 0, stream>>>(Wproj, WprojT, 1024L, 1024L);
    transpose_f2b_kernel<<<dim3(128, 32), tb, 0, stream>>>(W1,   W1T,    4096L, 1024L);
    transpose_f2b_kernel<<<dim3(32, 128), tb, 0, stream>>>(W2,   W2T,    1024L, 4096L);

    ln_kernel<float><<<8192, 256, 0, stream>>>(x, ln1g, ln1b, h, Dq);

    // kqv = h @ Wqkv + bqkv    [8192, 3072]
    gemm128<<<dim3(24, 64, 1), 256, 0, stream>>>(h, WqkvT, bqkv, kqv, nullptr,
        1024, 1024L, 1024L, 3072L, 0L, 0L, 0L, 1.f, 0, 0);

    // vT[b][d][t] = v[b][t][d]
    transpose_b2b_kernel<<<dim3(32, 64, 4), tb, 0, stream>>>(kqv + 2048, vT, 3072L, 2048L, T3D, DT);

    // scores = q @ k^T / sqrt(T), causal 128-tile skip
    gemm128<<<dim3(16, 16, 4), 256, 0, stream>>>(kqv + 1024, kqv, nullptr, attn, nullptr,
        1024, 3072L, 3072L, 2048L, T3D, T3D, TT, 0.022097086912079608f, 0, 1);

    softmax_kernel<<<8192, 256, 0, stream>>>(attn);

    // a = attn @ V
    gemm128<<<dim3(8, 16, 4), 256, 0, stream>>>(attn, vT, nullptr, a, nullptr,
        2048, 2048L, 2048L, 1024L, TT, DT, TD, 1.f, 0, 0);

    // p = a @ Wproj + bproj
    gemm128<<<dim3(8, 64, 1), 256, 0, stream>>>(a, WprojT, bproj, p, nullptr,
        1024, 1024L, 1024L, 1024L, 0L, 0L, 0L, 1.f, 0, 0);

    ln_kernel<bf16><<<8192, 256, 0, stream>>>(p, ln2g, ln2b, h2, Dq);

    // m = gelu(h2 @ W1 + b1)   [8192, 4096]
    gemm128<<<dim3(32, 64, 1), 256, 0, stream>>>(h2, W1T, b1, m, nullptr,
        1024, 1024L, 1024L, 4096L, 0L, 0L, 0L, 1.f, 1, 0);

    // out = m @ W2 + b2        [8192, 1024]  (fp32 out)
    gemm128<<<dim3(8, 64, 1), 256, 0, stream>>>(m, W2T, b2, nullptr, out,
        4096, 4096L, 4096L, 1024L, 0L, 0L, 0L, 1.f, 0, 0);
}

// Round 4
// 561.699 us; speedup vs baseline: 3.6318x; 1.0987x over previous
//
#include <hip/hip_runtime.h>
#include <hip/hip_bf16.h>

typedef __hip_bfloat16 bf16;
typedef __bf16 bf16x8 __attribute__((ext_vector_type(8)));
typedef __bf16 bf16x4 __attribute__((ext_vector_type(4)));
typedef float f32x4 __attribute__((ext_vector_type(4)));

static constexpr int Bq = 4, Tq = 2048, Dq = 1024;

__device__ inline float b2f(bf16 h) { return __bfloat162float(h); }
__device__ inline bf16 f2b(float f) { return __float2bfloat16(f); }

// async global->LDS, 16 B per lane. LDS dst = wave-uniform base + lane*16.
__device__ __forceinline__ void gload_lds16(const bf16* g, bf16* lds_wave_base) {
    __builtin_amdgcn_global_load_lds((const __attribute__((address_space(1))) void*)g,
                                     (__attribute__((address_space(3))) void*)lds_wave_base,
                                     16, 0, 0);
}

// fast tanh-approx GELU: x * sigmoid(1.5957691x + 0.0713548x^3), via exp2+rcp
__device__ __forceinline__ float fast_gelu(float x) {
    float u = x * (0.7978845608028654f + 0.03567740814183427f * x * x);
    float e = __builtin_amdgcn_exp2f(-2.885390081777927f * u);
    return x * __builtin_amdgcn_rcpf(1.f + e);
}

// ---------------- LayerNorm (one block per row, D=1024), fp32 gamma/beta ----------------
__device__ inline void ld4f(const float* p, float* v) {
    float4 t = *reinterpret_cast<const float4*>(p);
    v[0] = t.x; v[1] = t.y; v[2] = t.z; v[3] = t.w;
}
__device__ inline void ld4f(const bf16* p, float* v) {
    bf16x4 t = *reinterpret_cast<const bf16x4*>(p);
    v[0] = (float)t[0]; v[1] = (float)t[1]; v[2] = (float)t[2]; v[3] = (float)t[3];
}

template <typename Tin>
__global__ void ln_kernel(const Tin* __restrict__ x, const float* __restrict__ g,
                          const float* __restrict__ b, bf16* __restrict__ out)
{
    const int row = blockIdx.x;
    const int tid = threadIdx.x;
    const int s0 = tid * 4;
    const Tin* xr = x + (size_t)row * Dq;
    bf16* orow = out + (size_t)row * Dq;
    float v[4], gv[4], bv[4];
    ld4f(xr + s0, v);
    ld4f(g + s0, gv);
    ld4f(b + s0, bv);
    float sum = v[0] + v[1] + v[2] + v[3];
    float sq = v[0]*v[0] + v[1]*v[1] + v[2]*v[2] + v[3]*v[3];
    for (int o = 32; o > 0; o >>= 1) { sum += __shfl_xor(sum, o); sq += __shfl_xor(sq, o); }
    __shared__ float ssum[4], ssq[4];
    const int w = tid >> 6;
    if ((tid & 63) == 0) { ssum[w] = sum; ssq[w] = sq; }
    __syncthreads();
    const float ts = ssum[0] + ssum[1] + ssum[2] + ssum[3];
    const float tq = ssq[0] + ssq[1] + ssq[2] + ssq[3];
    const float mean = ts / Dq;
    const float rs = rsqrtf(tq / Dq - mean * mean + 1e-5f);
    bf16x4 o4;
    #pragma unroll
    for (int i = 0; i < 4; ++i) o4[i] = (__bf16)((v[i] - mean) * rs * gv[i] + bv[i]);
    *reinterpret_cast<bf16x4*>(orow + s0) = o4;
}

// ---------------- Tiled transpose fp32 -> bf16 ----------------
__global__ void transpose_f2b_kernel(const float* __restrict__ in, bf16* __restrict__ out,
                                     long ldin, long ldout)
{
    __shared__ float tile[32][33];
    const int c0 = blockIdx.x * 32, r0 = blockIdx.y * 32;
    const int tx = threadIdx.x, ty = threadIdx.y;
    for (int i = 0; i < 4; ++i) {
        int r = r0 + ty + i * 8;
        tile[ty + i * 8][tx] = in[(size_t)r * ldin + c0 + tx];
    }
    __syncthreads();
    for (int i = 0; i < 4; ++i) {
        int cc = ty + i * 8;
        out[(size_t)(c0 + cc) * ldout + r0 + tx] = f2b(tile[tx][cc]);
    }
}

// ---------------- Tiled transpose bf16 -> bf16 (for V^T) ----------------
__global__ void transpose_b2b_kernel(const bf16* __restrict__ in, bf16* __restrict__ out,
                                     long ldin, long ldout, long inBatch, long outBatch)
{
    __shared__ bf16 tile[32][33];
    const bf16* ip = in + (size_t)blockIdx.z * inBatch;
    bf16* op = out + (size_t)blockIdx.z * outBatch;
    const int c0 = blockIdx.x * 32, r0 = blockIdx.y * 32;
    const int tx = threadIdx.x, ty = threadIdx.y;
    for (int i = 0; i < 4; ++i) {
        int r = r0 + ty + i * 8;
        tile[ty + i * 8][tx] = ip[(size_t)r * ldin + c0 + tx];
    }
    __syncthreads();
    for (int i = 0; i < 4; ++i) {
        int cc = ty + i * 8;
        op[(size_t)(c0 + cc) * ldout + r0 + tx] = tile[tx][cc];
    }
}

// ---------------- Causal softmax, vectorized (one bf16x8 granule per thread) ----------------
__global__ void softmax_kernel(bf16* __restrict__ attn)
{
    const int row = blockIdx.x;
    const int bb = row >> 11;
    const int t = row & (Tq - 1);
    bf16* base = attn + (size_t)bb * Tq * Tq + (size_t)t * Tq;
    const int tid = threadIdx.x;
    const int len = t + 1;
    const int s0 = tid * 8;
    bf16x8 v8 = *reinterpret_cast<const bf16x8*>(base + s0);
    float ev[8];
    #pragma unroll
    for (int i = 0; i < 8; ++i) ev[i] = (s0 + i < len) ? (float)v8[i] : -1e30f;
    float mx = ev[0];
    #pragma unroll
    for (int i = 1; i < 8; ++i) mx = fmaxf(mx, ev[i]);
    for (int o = 32; o > 0; o >>= 1) mx = fmaxf(mx, __shfl_xor(mx, o));
    __shared__ float sred[4];
    const int w = tid >> 6;
    if ((tid & 63) == 0) sred[w] = mx;
    __syncthreads();
    mx = fmaxf(fmaxf(sred[0], sred[1]), fmaxf(sred[2], sred[3]));
    __syncthreads();
    float sum = 0.f;
    #pragma unroll
    for (int i = 0; i < 8; ++i) {
        ev[i] = (s0 + i < len) ? __builtin_amdgcn_exp2f(1.4426950408889634f * (ev[i] - mx)) : 0.f;
        sum += ev[i];
    }
    for (int o = 32; o > 0; o >>= 1) sum += __shfl_xor(sum, o);
    if ((tid & 63) == 0) sred[w] = sum;
    __syncthreads();
    const float inv = __builtin_amdgcn_rcpf(sred[0] + sred[1] + sred[2] + sred[3]);
    bf16x8 o8;
    #pragma unroll
    for (int i = 0; i < 8; ++i) o8[i] = (__bf16)(ev[i] * inv);
    *reinterpret_cast<bf16x8*>(base + s0) = o8;
}

// ---------------- 128x128 LDS-staged MFMA GEMM, XOR-swizzled LDS ----------------
// C = act(scale * A @ Bt^T + bias). A:[M,K] (lda), Bt:[N,K] (ldb), bf16.
// 256 threads = 4 waves 2x2; wave owns 64x64 quadrant = 4x4 MFMA 16x16x32 tiles.
// LDS tile 128x32; global k-granule g of row r stored at LDS granule col g^((r>>1)&3)
// => quarter-wave frag reads spread over all 8 bank-groups (2-way = free, m136).
__global__ void gemm128(const bf16* __restrict__ A, const bf16* __restrict__ Bt,
                        const float* __restrict__ bias,
                        bf16* __restrict__ Cb, float* __restrict__ Cf,
                        int K, long lda, long ldb, long ldc,
                        long sA, long sB, long sC,
                        float scale, int act, int causal)
{
    const int m0 = blockIdx.y * 128, n0 = blockIdx.x * 128;
    if (causal && n0 > m0 + 127) return;   // fully-masked tile; softmax writes the zeros

    __shared__ bf16 As[128 * 32];
    __shared__ bf16 Bs[128 * 32];

    const bf16* Ab = A + (size_t)blockIdx.z * sA;
    const bf16* Bb = Bt + (size_t)blockIdx.z * sB;
    const int tid = threadIdx.x;
    const int wid = tid >> 6, lane = tid & 63;
    const int wr = wid >> 1, wc = wid & 1;
    const int l15 = lane & 15, quad = lane >> 4;

    // staging: lane's LDS slot is granule (srow, lane&3); it fetches global granule
    // (lane&3) ^ ((srow>>1)&3) so data lands swizzled. Same scol valid for rows +64.
    const int srow = wid * 16 + (lane >> 2);
    const int scol = (((lane & 3) ^ ((srow >> 1) & 3))) * 8;
    const bf16* agp0 = Ab + (size_t)(m0 + srow) * lda + scol;
    const bf16* agp1 = Ab + (size_t)(m0 + 64 + srow) * lda + scol;
    const bf16* bgp0 = Bb + (size_t)(n0 + srow) * ldb + scol;
    const bf16* bgp1 = Bb + (size_t)(n0 + 64 + srow) * ldb + scol;
    bf16* aw0 = As + wid * 512;
    bf16* aw1 = As + 2048 + wid * 512;
    bf16* bw0 = Bs + wid * 512;
    bf16* bw1 = Bs + 2048 + wid * 512;

    // fragment read offsets: row = base + l15; swizzle xor = (l15>>1)&3 (constant
    // across i/j since wr*64, i*16 are 0 mod 8)
    const int xsw = (l15 >> 1) & 3;
    const int afo = (wr * 64 + l15) * 32 + (quad ^ xsw) * 8;
    const int bfo = (wc * 64 + l15) * 32 + (quad ^ xsw) * 8;

    f32x4 acc[4][4];
    #pragma unroll
    for (int i = 0; i < 4; ++i)
        #pragma unroll
        for (int j = 0; j < 4; ++j) acc[i][j] = (f32x4){0.f, 0.f, 0.f, 0.f};

    for (int k0 = 0; k0 < K; k0 += 32) {
        gload_lds16(agp0 + k0, aw0);
        gload_lds16(agp1 + k0, aw1);
        gload_lds16(bgp0 + k0, bw0);
        gload_lds16(bgp1 + k0, bw1);
        __syncthreads();   // drains vmcnt: LDS tile complete

        bf16x8 af[4], bff[4];
        #pragma unroll
        for (int i = 0; i < 4; ++i) af[i] = *reinterpret_cast<const bf16x8*>(As + afo + i * 512);
        #pragma unroll
        for (int j = 0; j < 4; ++j) bff[j] = *reinterpret_cast<const bf16x8*>(Bs + bfo + j * 512);
        #pragma unroll
        for (int i = 0; i < 4; ++i)
            #pragma unroll
            for (int j = 0; j < 4; ++j)
                acc[i][j] = __builtin_amdgcn_mfma_f32_16x16x32_bf16(af[i], bff[j], acc[i][j], 0, 0, 0);

        __syncthreads();   // protect LDS before next iteration overwrites
    }

    // epilogue: C/D layout row=quad*4+reg, col=l15 (m89/m91-verified)
    #pragma unroll
    for (int i = 0; i < 4; ++i) {
        const int row = m0 + wr * 64 + i * 16 + quad * 4;
        #pragma unroll
        for (int j = 0; j < 4; ++j) {
            const int col = n0 + wc * 64 + j * 16 + l15;
            const float bv = bias ? bias[col] : 0.f;
            #pragma unroll
            for (int r = 0; r < 4; ++r) {
                float vv = scale * acc[i][j][r] + bv;
                if (act == 1) vv = fast_gelu(vv);
                const size_t idx = (size_t)(row + r) * ldc + col + (size_t)blockIdx.z * sC;
                if (Cf) Cf[idx] = vv;
                else    Cb[idx] = f2b(vv);
            }
        }
    }
}

extern "C" void kernel_launch(void* const* d_in, const int* in_sizes, int n_in,
                              void* d_out, int out_size, void* d_ws, size_t ws_size,
                              hipStream_t stream)
{
    (void)in_sizes; (void)n_in; (void)out_size; (void)ws_size;
    const float* x     = (const float*)d_in[0];
    const float* ln1g  = (const float*)d_in[1];
    const float* ln1b  = (const float*)d_in[2];
    const float* Wqkv  = (const float*)d_in[3];
    const float* bqkv  = (const float*)d_in[4];
    const float* Wproj = (const float*)d_in[5];
    const float* bproj = (const float*)d_in[6];
    const float* ln2g  = (const float*)d_in[7];
    const float* ln2b  = (const float*)d_in[8];
    const float* W1    = (const float*)d_in[9];
    const float* b1    = (const float*)d_in[10];
    const float* W2    = (const float*)d_in[11];
    const float* b2    = (const float*)d_in[12];
    float* out = (float*)d_out;

    // ---- workspace arena (bf16 elements) ----
    char* ws = (char*)d_ws;
    size_t off = 0;
    auto alloc = [&](size_t elems) { bf16* p = (bf16*)(ws + off); off += elems * sizeof(bf16); return p; };
    bf16* WqkvT  = alloc(3072UL * 1024);
    bf16* WprojT = alloc(1024UL * 1024);
    bf16* W1T    = alloc(4096UL * 1024);
    bf16* W2T    = alloc(1024UL * 4096);
    bf16* h      = alloc(8192UL * 1024);        // LN1 out; later reused as `a`
    bf16* kqv    = alloc(8192UL * 3072);        // per-row k|q|v
    bf16* vT     = alloc(4UL * 1024 * 2048);
    bf16* attn   = alloc(4UL * 2048 * 2048);
    // aliases (lifetimes disjoint):
    bf16* a   = h;
    bf16* p   = kqv;
    bf16* h2  = kqv + 8192UL * 1024;
    bf16* m   = kqv + 2UL * 8192 * 1024;        // spans kqv-tail + vT + attn

    const dim3 tb(32, 8);
    const long T3D = (long)Tq * 3072, TT = (long)Tq * Tq, DT = (long)Dq * Tq, TD = (long)Tq * Dq;

    transpose_f2b_kernel<<<dim3(96, 32), tb, 0, stream>>>(Wqkv,  WqkvT,  3072L, 1024L);
    transpose_f2b_kernel<<<dim3(32, 32), tb, 0, stream>>>(Wproj, WprojT, 1024L, 1024L);
    transpose_f2b_kernel<<<dim3(128, 32), tb, 0, stream>>>(W1,   W1T,    4096L, 1024L);
    transpose_f2b_kernel<<<dim3(32, 128), tb, 0, stream>>>(W2,   W2T,    1024L, 4096L);

    ln_kernel<float><<<8192, 256, 0, stream>>>(x, ln1g, ln1b, h);

    // kqv = h @ Wqkv + bqkv    [8192, 3072]
    gemm128<<<dim3(24, 64, 1), 256, 0, stream>>>(h, WqkvT, bqkv, kqv, nullptr,
        1024, 1024L, 1024L, 3072L, 0L, 0L, 0L, 1.f, 0, 0);

    // vT[b][d][t] = v[b][t][d]
    transpose_b2b_kernel<<<dim3(32, 64, 4), tb, 0, stream>>>(kqv + 2048, vT, 3072L, 2048L, T3D, DT);

    // scores = q @ k^T / sqrt(T), causal 128-tile skip
    gemm128<<<dim3(16, 16, 4), 256, 0, stream>>>(kqv + 1024, kqv, nullptr, attn, nullptr,
        1024, 3072L, 3072L, 2048L, T3D, T3D, TT, 0.022097086912079608f, 0, 1);

    softmax_kernel<<<8192, 256, 0, stream>>>(attn);

    // a = attn @ V
    gemm128<<<dim3(8, 16, 4), 256, 0, stream>>>(attn, vT, nullptr, a, nullptr,
        2048, 2048L, 2048L, 1024L, TT, DT, TD, 1.f, 0, 0);

    // p = a @ Wproj + bproj
    gemm128<<<dim3(8, 64, 1), 256, 0, stream>>>(a, WprojT, bproj, p, nullptr,
        1024, 1024L, 1024L, 1024L, 0L, 0L, 0L, 1.f, 0, 0);

    ln_kernel<bf16><<<8192, 256, 0, stream>>>(p, ln2g, ln2b, h2);

    // m = gelu(h2 @ W1 + b1)   [8192, 4096]
    gemm128<<<dim3(32, 64, 1), 256, 0, stream>>>(h2, W1T, b1, m, nullptr,
        1024, 1024L, 1024L, 4096L, 0L, 0L, 0L, 1.f, 1, 0);

    // out = m @ W2 + b2        [8192, 1024]  (fp32 out)
    gemm128<<<dim3(8, 64, 1), 256, 0, stream>>>(m, W2T, b2, nullptr, out,
        4096, 4096L, 4096L, 1024L, 0L, 0L, 0L, 1.f, 0, 0);
}

// Round 5
// 559.621 us; speedup vs baseline: 3.6452x; 1.0037x over previous
//
#include <hip/hip_runtime.h>
#include <hip/hip_bf16.h>

typedef __hip_bfloat16 bf16;
typedef __bf16 bf16x8 __attribute__((ext_vector_type(8)));
typedef __bf16 bf16x4 __attribute__((ext_vector_type(4)));
typedef float f32x4 __attribute__((ext_vector_type(4)));

static constexpr int Bq = 4, Tq = 2048, Dq = 1024;

__device__ inline float b2f(bf16 h) { return __bfloat162float(h); }
__device__ inline bf16 f2b(float f) { return __float2bfloat16(f); }

// async global->LDS, 16 B per lane. LDS dst = wave-uniform base + lane*16.
__device__ __forceinline__ void gload_lds16(const bf16* g, bf16* lds_wave_base) {
    __builtin_amdgcn_global_load_lds((const __attribute__((address_space(1))) void*)g,
                                     (__attribute__((address_space(3))) void*)lds_wave_base,
                                     16, 0, 0);
}

// fast tanh-approx GELU: x * sigmoid(1.5957691x + 0.0713548x^3), via exp2+rcp
__device__ __forceinline__ float fast_gelu(float x) {
    float u = x * (0.7978845608028654f + 0.03567740814183427f * x * x);
    float e = __builtin_amdgcn_exp2f(-2.885390081777927f * u);
    return x * __builtin_amdgcn_rcpf(1.f + e);
}

// ---------------- LayerNorm (one block per row, D=1024), fp32 gamma/beta ----------------
__device__ inline void ld4f(const float* p, float* v) {
    float4 t = *reinterpret_cast<const float4*>(p);
    v[0] = t.x; v[1] = t.y; v[2] = t.z; v[3] = t.w;
}
__device__ inline void ld4f(const bf16* p, float* v) {
    bf16x4 t = *reinterpret_cast<const bf16x4*>(p);
    v[0] = (float)t[0]; v[1] = (float)t[1]; v[2] = (float)t[2]; v[3] = (float)t[3];
}

template <typename Tin>
__global__ void ln_kernel(const Tin* __restrict__ x, const float* __restrict__ g,
                          const float* __restrict__ b, bf16* __restrict__ out)
{
    const int row = blockIdx.x;
    const int tid = threadIdx.x;
    const int s0 = tid * 4;
    const Tin* xr = x + (size_t)row * Dq;
    bf16* orow = out + (size_t)row * Dq;
    float v[4], gv[4], bv[4];
    ld4f(xr + s0, v);
    ld4f(g + s0, gv);
    ld4f(b + s0, bv);
    float sum = v[0] + v[1] + v[2] + v[3];
    float sq = v[0]*v[0] + v[1]*v[1] + v[2]*v[2] + v[3]*v[3];
    for (int o = 32; o > 0; o >>= 1) { sum += __shfl_xor(sum, o); sq += __shfl_xor(sq, o); }
    __shared__ float ssum[4], ssq[4];
    const int w = tid >> 6;
    if ((tid & 63) == 0) { ssum[w] = sum; ssq[w] = sq; }
    __syncthreads();
    const float ts = ssum[0] + ssum[1] + ssum[2] + ssum[3];
    const float tq = ssq[0] + ssq[1] + ssq[2] + ssq[3];
    const float mean = ts / Dq;
    const float rs = rsqrtf(tq / Dq - mean * mean + 1e-5f);
    bf16x4 o4;
    #pragma unroll
    for (int i = 0; i < 4; ++i) o4[i] = (__bf16)((v[i] - mean) * rs * gv[i] + bv[i]);
    *reinterpret_cast<bf16x4*>(orow + s0) = o4;
}

// ---------------- Tiled transpose fp32 -> bf16 ----------------
__global__ void transpose_f2b_kernel(const float* __restrict__ in, bf16* __restrict__ out,
                                     long ldin, long ldout)
{
    __shared__ float tile[32][33];
    const int c0 = blockIdx.x * 32, r0 = blockIdx.y * 32;
    const int tx = threadIdx.x, ty = threadIdx.y;
    for (int i = 0; i < 4; ++i) {
        int r = r0 + ty + i * 8;
        tile[ty + i * 8][tx] = in[(size_t)r * ldin + c0 + tx];
    }
    __syncthreads();
    for (int i = 0; i < 4; ++i) {
        int cc = ty + i * 8;
        out[(size_t)(c0 + cc) * ldout + r0 + tx] = f2b(tile[tx][cc]);
    }
}

// ---------------- Tiled transpose bf16 -> bf16 (for V^T) ----------------
__global__ void transpose_b2b_kernel(const bf16* __restrict__ in, bf16* __restrict__ out,
                                     long ldin, long ldout, long inBatch, long outBatch)
{
    __shared__ bf16 tile[32][33];
    const bf16* ip = in + (size_t)blockIdx.z * inBatch;
    bf16* op = out + (size_t)blockIdx.z * outBatch;
    const int c0 = blockIdx.x * 32, r0 = blockIdx.y * 32;
    const int tx = threadIdx.x, ty = threadIdx.y;
    for (int i = 0; i < 4; ++i) {
        int r = r0 + ty + i * 8;
        tile[ty + i * 8][tx] = ip[(size_t)r * ldin + c0 + tx];
    }
    __syncthreads();
    for (int i = 0; i < 4; ++i) {
        int cc = ty + i * 8;
        op[(size_t)(c0 + cc) * ldout + r0 + tx] = tile[tx][cc];
    }
}

// ---------------- Causal softmax, vectorized (one bf16x8 granule per thread) ----------------
__global__ void softmax_kernel(bf16* __restrict__ attn)
{
    const int row = blockIdx.x;
    const int bb = row >> 11;
    const int t = row & (Tq - 1);
    bf16* base = attn + (size_t)bb * Tq * Tq + (size_t)t * Tq;
    const int tid = threadIdx.x;
    const int len = t + 1;
    const int s0 = tid * 8;
    bf16x8 v8 = *reinterpret_cast<const bf16x8*>(base + s0);
    float ev[8];
    #pragma unroll
    for (int i = 0; i < 8; ++i) ev[i] = (s0 + i < len) ? (float)v8[i] : -1e30f;
    float mx = ev[0];
    #pragma unroll
    for (int i = 1; i < 8; ++i) mx = fmaxf(mx, ev[i]);
    for (int o = 32; o > 0; o >>= 1) mx = fmaxf(mx, __shfl_xor(mx, o));
    __shared__ float sred[4];
    const int w = tid >> 6;
    if ((tid & 63) == 0) sred[w] = mx;
    __syncthreads();
    mx = fmaxf(fmaxf(sred[0], sred[1]), fmaxf(sred[2], sred[3]));
    __syncthreads();
    float sum = 0.f;
    #pragma unroll
    for (int i = 0; i < 8; ++i) {
        ev[i] = (s0 + i < len) ? __builtin_amdgcn_exp2f(1.4426950408889634f * (ev[i] - mx)) : 0.f;
        sum += ev[i];
    }
    for (int o = 32; o > 0; o >>= 1) sum += __shfl_xor(sum, o);
    if ((tid & 63) == 0) sred[w] = sum;
    __syncthreads();
    const float inv = __builtin_amdgcn_rcpf(sred[0] + sred[1] + sred[2] + sred[3]);
    bf16x8 o8;
    #pragma unroll
    for (int i = 0; i < 8; ++i) o8[i] = (__bf16)(ev[i] * inv);
    *reinterpret_cast<bf16x8*>(base + s0) = o8;
}

// ---------------- 128x128 LDS-staged MFMA GEMM, XOR-swizzled LDS, XCD-banded grid ----------------
// C = act(scale * A @ Bt^T + bias). A:[M,K] (lda), Bt:[N,K] (ldb), bf16.
// 256 threads = 4 waves 2x2; wave owns 64x64 quadrant = 4x4 MFMA 16x16x32 tiles.
// Grid remap: band = lin&7 (XCD heuristic) gets contiguous row-band so A-strips are
// filled into exactly one XCD L2 (R4: MLP2 fetched 272MB vs 75MB ideal from cross-XCD refill).
// causalK: A columns >= m0+128 are known-zero (post-softmax attn) -> truncate K loop.
__global__ void gemm128(const bf16* __restrict__ A, const bf16* __restrict__ Bt,
                        const float* __restrict__ bias,
                        bf16* __restrict__ Cb, float* __restrict__ Cf,
                        int K, long lda, long ldb, long ldc,
                        long sA, long sB, long sC,
                        float scale, int act, int causal, int causalK)
{
    // ---- XCD-banded remap (bijective; gy % 8 == 0 for all our grids) ----
    const int gx = gridDim.x, gy = gridDim.y;
    int lin = blockIdx.x + gx * blockIdx.y;
    const int band = lin & 7;
    const int idx = lin >> 3;
    const int bx = idx % gx;
    const int by = band * (gy >> 3) + idx / gx;

    const int m0 = by * 128, n0 = bx * 128;
    if (causal && n0 > m0 + 127) return;   // fully-masked tile; softmax writes the zeros
    const int Kend = causalK ? min(K, m0 + 128) : K;

    __shared__ bf16 As[128 * 32];
    __shared__ bf16 Bs[128 * 32];

    const bf16* Ab = A + (size_t)blockIdx.z * sA;
    const bf16* Bb = Bt + (size_t)blockIdx.z * sB;
    const int tid = threadIdx.x;
    const int wid = tid >> 6, lane = tid & 63;
    const int wr = wid >> 1, wc = wid & 1;
    const int l15 = lane & 15, quad = lane >> 4;

    // staging: lane's LDS slot is granule (srow, lane&3); it fetches global granule
    // (lane&3) ^ ((srow>>1)&3) so data lands swizzled (bank-conflict-free frag reads).
    const int srow = wid * 16 + (lane >> 2);
    const int scol = (((lane & 3) ^ ((srow >> 1) & 3))) * 8;
    const bf16* agp0 = Ab + (size_t)(m0 + srow) * lda + scol;
    const bf16* agp1 = Ab + (size_t)(m0 + 64 + srow) * lda + scol;
    const bf16* bgp0 = Bb + (size_t)(n0 + srow) * ldb + scol;
    const bf16* bgp1 = Bb + (size_t)(n0 + 64 + srow) * ldb + scol;
    bf16* aw0 = As + wid * 512;
    bf16* aw1 = As + 2048 + wid * 512;
    bf16* bw0 = Bs + wid * 512;
    bf16* bw1 = Bs + 2048 + wid * 512;

    // fragment read offsets: swizzle xor = (l15>>1)&3 (constant across i/j)
    const int xsw = (l15 >> 1) & 3;
    const int afo = (wr * 64 + l15) * 32 + (quad ^ xsw) * 8;
    const int bfo = (wc * 64 + l15) * 32 + (quad ^ xsw) * 8;

    f32x4 acc[4][4];
    #pragma unroll
    for (int i = 0; i < 4; ++i)
        #pragma unroll
        for (int j = 0; j < 4; ++j) acc[i][j] = (f32x4){0.f, 0.f, 0.f, 0.f};

    for (int k0 = 0; k0 < Kend; k0 += 32) {
        gload_lds16(agp0 + k0, aw0);
        gload_lds16(agp1 + k0, aw1);
        gload_lds16(bgp0 + k0, bw0);
        gload_lds16(bgp1 + k0, bw1);
        __syncthreads();   // drains vmcnt: LDS tile complete

        bf16x8 af[4], bff[4];
        #pragma unroll
        for (int i = 0; i < 4; ++i) af[i] = *reinterpret_cast<const bf16x8*>(As + afo + i * 512);
        #pragma unroll
        for (int j = 0; j < 4; ++j) bff[j] = *reinterpret_cast<const bf16x8*>(Bs + bfo + j * 512);
        #pragma unroll
        for (int i = 0; i < 4; ++i)
            #pragma unroll
            for (int j = 0; j < 4; ++j)
                acc[i][j] = __builtin_amdgcn_mfma_f32_16x16x32_bf16(af[i], bff[j], acc[i][j], 0, 0, 0);

        __syncthreads();   // protect LDS before next iteration overwrites
    }

    // epilogue: C/D layout row=quad*4+reg, col=l15 (m89/m91-verified)
    #pragma unroll
    for (int i = 0; i < 4; ++i) {
        const int row = m0 + wr * 64 + i * 16 + quad * 4;
        #pragma unroll
        for (int j = 0; j < 4; ++j) {
            const int col = n0 + wc * 64 + j * 16 + l15;
            const float bv = bias ? bias[col] : 0.f;
            #pragma unroll
            for (int r = 0; r < 4; ++r) {
                float vv = scale * acc[i][j][r] + bv;
                if (act == 1) vv = fast_gelu(vv);
                const size_t idx2 = (size_t)(row + r) * ldc + col + (size_t)blockIdx.z * sC;
                if (Cf) Cf[idx2] = vv;
                else    Cb[idx2] = f2b(vv);
            }
        }
    }
}

extern "C" void kernel_launch(void* const* d_in, const int* in_sizes, int n_in,
                              void* d_out, int out_size, void* d_ws, size_t ws_size,
                              hipStream_t stream)
{
    (void)in_sizes; (void)n_in; (void)out_size; (void)ws_size;
    const float* x     = (const float*)d_in[0];
    const float* ln1g  = (const float*)d_in[1];
    const float* ln1b  = (const float*)d_in[2];
    const float* Wqkv  = (const float*)d_in[3];
    const float* bqkv  = (const float*)d_in[4];
    const float* Wproj = (const float*)d_in[5];
    const float* bproj = (const float*)d_in[6];
    const float* ln2g  = (const float*)d_in[7];
    const float* ln2b  = (const float*)d_in[8];
    const float* W1    = (const float*)d_in[9];
    const float* b1    = (const float*)d_in[10];
    const float* W2    = (const float*)d_in[11];
    const float* b2    = (const float*)d_in[12];
    float* out = (float*)d_out;

    // ---- workspace arena (bf16 elements) ----
    char* ws = (char*)d_ws;
    size_t off = 0;
    auto alloc = [&](size_t elems) { bf16* p = (bf16*)(ws + off); off += elems * sizeof(bf16); return p; };
    bf16* WqkvT  = alloc(3072UL * 1024);
    bf16* WprojT = alloc(1024UL * 1024);
    bf16* W1T    = alloc(4096UL * 1024);
    bf16* W2T    = alloc(1024UL * 4096);
    bf16* h      = alloc(8192UL * 1024);        // LN1 out; later reused as `a`
    bf16* kqv    = alloc(8192UL * 3072);        // per-row k|q|v
    bf16* vT     = alloc(4UL * 1024 * 2048);
    bf16* attn   = alloc(4UL * 2048 * 2048);
    // aliases (lifetimes disjoint):
    bf16* a   = h;
    bf16* p   = kqv;
    bf16* h2  = kqv + 8192UL * 1024;
    bf16* m   = kqv + 2UL * 8192 * 1024;        // spans kqv-tail + vT + attn

    const dim3 tb(32, 8);
    const long T3D = (long)Tq * 3072, TT = (long)Tq * Tq, DT = (long)Dq * Tq, TD = (long)Tq * Dq;

    transpose_f2b_kernel<<<dim3(96, 32), tb, 0, stream>>>(Wqkv,  WqkvT,  3072L, 1024L);
    transpose_f2b_kernel<<<dim3(32, 32), tb, 0, stream>>>(Wproj, WprojT, 1024L, 1024L);
    transpose_f2b_kernel<<<dim3(128, 32), tb, 0, stream>>>(W1,   W1T,    4096L, 1024L);
    transpose_f2b_kernel<<<dim3(32, 128), tb, 0, stream>>>(W2,   W2T,    1024L, 4096L);

    ln_kernel<float><<<8192, 256, 0, stream>>>(x, ln1g, ln1b, h);

    // kqv = h @ Wqkv + bqkv    [8192, 3072]
    gemm128<<<dim3(24, 64, 1), 256, 0, stream>>>(h, WqkvT, bqkv, kqv, nullptr,
        1024, 1024L, 1024L, 3072L, 0L, 0L, 0L, 1.f, 0, 0, 0);

    // vT[b][d][t] = v[b][t][d]
    transpose_b2b_kernel<<<dim3(32, 64, 4), tb, 0, stream>>>(kqv + 2048, vT, 3072L, 2048L, T3D, DT);

    // scores = q @ k^T / sqrt(T), causal 128-tile skip
    gemm128<<<dim3(16, 16, 4), 256, 0, stream>>>(kqv + 1024, kqv, nullptr, attn, nullptr,
        1024, 3072L, 3072L, 2048L, T3D, T3D, TT, 0.022097086912079608f, 0, 1, 0);

    softmax_kernel<<<8192, 256, 0, stream>>>(attn);

    // a = attn @ V   (K truncated to m0+128: attn cols > row are zero)
    gemm128<<<dim3(8, 16, 4), 256, 0, stream>>>(attn, vT, nullptr, a, nullptr,
        2048, 2048L, 2048L, 1024L, TT, DT, TD, 1.f, 0, 0, 1);

    // p = a @ Wproj + bproj
    gemm128<<<dim3(8, 64, 1), 256, 0, stream>>>(a, WprojT, bproj, p, nullptr,
        1024, 1024L, 1024L, 1024L, 0L, 0L, 0L, 1.f, 0, 0, 0);

    ln_kernel<bf16><<<8192, 256, 0, stream>>>(p, ln2g, ln2b, h2);

    // m = gelu(h2 @ W1 + b1)   [8192, 4096]
    gemm128<<<dim3(32, 64, 1), 256, 0, stream>>>(h2, W1T, b1, m, nullptr,
        1024, 1024L, 1024L, 4096L, 0L, 0L, 0L, 1.f, 1, 0, 0);

    // out = m @ W2 + b2        [8192, 1024]  (fp32 out)
    gemm128<<<dim3(8, 64, 1), 256, 0, stream>>>(m, W2T, b2, nullptr, out,
        4096, 4096L, 4096L, 1024L, 0L, 0L, 0L, 1.f, 0, 0, 0);
}

// Round 6
// 552.654 us; speedup vs baseline: 3.6912x; 1.0126x over previous
//
#include <hip/hip_runtime.h>
#include <hip/hip_bf16.h>

typedef __hip_bfloat16 bf16;
typedef __bf16 bf16x8 __attribute__((ext_vector_type(8)));
typedef __bf16 bf16x4 __attribute__((ext_vector_type(4)));
typedef __bf16 bf16x2 __attribute__((ext_vector_type(2)));
typedef float f32x4 __attribute__((ext_vector_type(4)));

static constexpr int Bq = 4, Tq = 2048, Dq = 1024;

__device__ inline float b2f(bf16 h) { return __bfloat162float(h); }
__device__ inline bf16 f2b(float f) { return __float2bfloat16(f); }

// async global->LDS, 16 B per lane. LDS dst = wave-uniform base + lane*16.
__device__ __forceinline__ void gload_lds16(const bf16* g, bf16* lds_wave_base) {
    __builtin_amdgcn_global_load_lds((const __attribute__((address_space(1))) void*)g,
                                     (__attribute__((address_space(3))) void*)lds_wave_base,
                                     16, 0, 0);
}

// fast tanh-approx GELU: x * sigmoid(1.5957691x + 0.0713548x^3), via exp2+rcp
__device__ __forceinline__ float fast_gelu(float x) {
    float u = x * (0.7978845608028654f + 0.03567740814183427f * x * x);
    float e = __builtin_amdgcn_exp2f(-2.885390081777927f * u);
    return x * __builtin_amdgcn_rcpf(1.f + e);
}

// ---------------- LayerNorm (one block per row, D=1024), fp32 gamma/beta ----------------
__device__ inline void ld4f(const float* p, float* v) {
    float4 t = *reinterpret_cast<const float4*>(p);
    v[0] = t.x; v[1] = t.y; v[2] = t.z; v[3] = t.w;
}
__device__ inline void ld4f(const bf16* p, float* v) {
    bf16x4 t = *reinterpret_cast<const bf16x4*>(p);
    v[0] = (float)t[0]; v[1] = (float)t[1]; v[2] = (float)t[2]; v[3] = (float)t[3];
}

template <typename Tin>
__global__ void ln_kernel(const Tin* __restrict__ x, const float* __restrict__ g,
                          const float* __restrict__ b, bf16* __restrict__ out)
{
    const int row = blockIdx.x;
    const int tid = threadIdx.x;
    const int s0 = tid * 4;
    const Tin* xr = x + (size_t)row * Dq;
    bf16* orow = out + (size_t)row * Dq;
    float v[4], gv[4], bv[4];
    ld4f(xr + s0, v);
    ld4f(g + s0, gv);
    ld4f(b + s0, bv);
    float sum = v[0] + v[1] + v[2] + v[3];
    float sq = v[0]*v[0] + v[1]*v[1] + v[2]*v[2] + v[3]*v[3];
    for (int o = 32; o > 0; o >>= 1) { sum += __shfl_xor(sum, o); sq += __shfl_xor(sq, o); }
    __shared__ float ssum[4], ssq[4];
    const int w = tid >> 6;
    if ((tid & 63) == 0) { ssum[w] = sum; ssq[w] = sq; }
    __syncthreads();
    const float ts = ssum[0] + ssum[1] + ssum[2] + ssum[3];
    const float tq = ssq[0] + ssq[1] + ssq[2] + ssq[3];
    const float mean = ts / Dq;
    const float rs = rsqrtf(tq / Dq - mean * mean + 1e-5f);
    bf16x4 o4;
    #pragma unroll
    for (int i = 0; i < 4; ++i) o4[i] = (__bf16)((v[i] - mean) * rs * gv[i] + bv[i]);
    *reinterpret_cast<bf16x4*>(orow + s0) = o4;
}

// ---------------- 64x64 pair-vectorized transpose fp32 -> bf16 ----------------
// grid: (cols/64, rows/64), block: 256. Reads fp32 coalesced; writes bf16x2 (u32).
__global__ void transpose_f2b_kernel(const float* __restrict__ in, bf16* __restrict__ out,
                                     long ldin, long ldout)
{
    __shared__ float tile[64][65];
    const int c0 = blockIdx.x * 64, r0 = blockIdx.y * 64;
    const int tid = threadIdx.x;
    const int tx = tid & 63, ty = tid >> 6;
    #pragma unroll
    for (int i = 0; i < 16; ++i) {
        int r = ty + i * 4;
        tile[r][tx] = in[(size_t)(r0 + r) * ldin + c0 + tx];
    }
    __syncthreads();
    const int px = tid & 31, cy = tid >> 5;
    #pragma unroll
    for (int i = 0; i < 8; ++i) {
        int cc = cy + i * 8;
        bf16x2 p;
        p[0] = (__bf16)tile[px * 2][cc];
        p[1] = (__bf16)tile[px * 2 + 1][cc];
        *reinterpret_cast<bf16x2*>(&out[(size_t)(c0 + cc) * ldout + r0 + px * 2]) = p;
    }
}

// ---------------- 64x64 pair-vectorized transpose bf16 -> bf16 (for V^T) ----------------
__global__ void transpose_b2b_kernel(const bf16* __restrict__ in, bf16* __restrict__ out,
                                     long ldin, long ldout, long inBatch, long outBatch)
{
    __shared__ bf16 tile[64][66];
    const bf16* ip = in + (size_t)blockIdx.z * inBatch;
    bf16* op = out + (size_t)blockIdx.z * outBatch;
    const int c0 = blockIdx.x * 64, r0 = blockIdx.y * 64;
    const int tid = threadIdx.x;
    const int tx = tid & 31, ty = tid >> 5;
    #pragma unroll
    for (int i = 0; i < 8; ++i) {
        int r = ty + i * 8;
        *reinterpret_cast<bf16x2*>(&tile[r][tx * 2]) =
            *reinterpret_cast<const bf16x2*>(&ip[(size_t)(r0 + r) * ldin + c0 + tx * 2]);
    }
    __syncthreads();
    #pragma unroll
    for (int i = 0; i < 8; ++i) {
        int cc = ty + i * 8;
        bf16x2 p;
        p[0] = tile[tx * 2][cc];
        p[1] = tile[tx * 2 + 1][cc];
        *reinterpret_cast<bf16x2*>(&op[(size_t)(c0 + cc) * ldout + r0 + tx * 2]) = p;
    }
}

// ---------------- Row-sum of unnormalized probs -> reciprocal ----------------
// P-hat rows: only s <= t are valid (written); beyond is untouched ws memory.
__global__ void rowsum_kernel(const bf16* __restrict__ attn, float* __restrict__ invl)
{
    const int row = blockIdx.x;
    const int t = row & (Tq - 1);
    const bf16* base = attn + (size_t)(row >> 11) * Tq * Tq + (size_t)t * Tq;
    const int tid = threadIdx.x;
    const int len = t + 1;
    const int s0 = tid * 8;
    bf16x8 v = *reinterpret_cast<const bf16x8*>(base + s0);  // always in-bounds of buffer
    float sum = 0.f;
    #pragma unroll
    for (int i = 0; i < 8; ++i) sum += (s0 + i < len) ? (float)v[i] : 0.f;
    for (int o = 32; o > 0; o >>= 1) sum += __shfl_xor(sum, o);
    __shared__ float sred[4];
    const int w = tid >> 6;
    if ((tid & 63) == 0) sred[w] = sum;
    __syncthreads();
    if (tid == 0) invl[row] = 1.f / (sred[0] + sred[1] + sred[2] + sred[3]);
}

// ---------------- 128x128 LDS-staged MFMA GEMM ----------------
// C = act(scale * A @ Bt^T + bias) [* rowscale]. A:[M,K] (lda), Bt:[N,K] (ldb), bf16.
// 256 threads = 4 waves 2x2; wave owns 64x64 quadrant = 4x4 MFMA 16x16x32 tiles.
// tri=1: grid.x indexes lower-triangle tiles (scores); act==2: exp2 epilogue with
// causal mask (scores are O(1) -> exp without max-subtraction is safe).
// rowscale: per-output-row multiplier (attn@V normalization by 1/l).
// causalK: A cols >= m0+128 known-zero -> truncate K loop.
__global__ void gemm128(const bf16* __restrict__ A, const bf16* __restrict__ Bt,
                        const float* __restrict__ bias, const float* __restrict__ rowscale,
                        bf16* __restrict__ Cb, float* __restrict__ Cf,
                        int K, long lda, long ldb, long ldc,
                        long sA, long sB, long sC,
                        float scale, int act, int tri, int causalK)
{
    int bx, by;
    if (tri) {
        // decode lower-triangle pair: by >= bx
        const int lin = blockIdx.x;
        int t = (int)((sqrtf(8.f * lin + 1.f) - 1.f) * 0.5f);
        while ((t + 1) * (t + 2) / 2 <= lin) ++t;
        while (t * (t + 1) / 2 > lin) --t;
        by = t; bx = lin - t * (t + 1) / 2;
    } else {
        // XCD-banded remap (bijective; gy % 8 == 0 for all our grids)
        const int gx = gridDim.x, gy = gridDim.y;
        const int lin = blockIdx.x + gx * blockIdx.y;
        const int band = lin & 7;
        const int idx = lin >> 3;
        bx = idx % gx;
        by = band * (gy >> 3) + idx / gx;
    }

    const int m0 = by * 128, n0 = bx * 128;
    const int Kend = causalK ? min(K, m0 + 128) : K;

    __shared__ bf16 As[128 * 32];
    __shared__ bf16 Bs[128 * 32];

    const bf16* Ab = A + (size_t)blockIdx.z * sA;
    const bf16* Bb = Bt + (size_t)blockIdx.z * sB;
    const int tid = threadIdx.x;
    const int wid = tid >> 6, lane = tid & 63;
    const int wr = wid >> 1, wc = wid & 1;
    const int l15 = lane & 15, quad = lane >> 4;

    // staging: lane's LDS slot is granule (srow, lane&3); fetches global granule
    // (lane&3) ^ ((srow>>1)&3) so data lands swizzled (bank-conflict-free frag reads).
    const int srow = wid * 16 + (lane >> 2);
    const int scol = (((lane & 3) ^ ((srow >> 1) & 3))) * 8;
    const bf16* agp0 = Ab + (size_t)(m0 + srow) * lda + scol;
    const bf16* agp1 = Ab + (size_t)(m0 + 64 + srow) * lda + scol;
    const bf16* bgp0 = Bb + (size_t)(n0 + srow) * ldb + scol;
    const bf16* bgp1 = Bb + (size_t)(n0 + 64 + srow) * ldb + scol;
    bf16* aw0 = As + wid * 512;
    bf16* aw1 = As + 2048 + wid * 512;
    bf16* bw0 = Bs + wid * 512;
    bf16* bw1 = Bs + 2048 + wid * 512;

    // fragment read offsets: swizzle xor = (l15>>1)&3 (constant across i/j)
    const int xsw = (l15 >> 1) & 3;
    const int afo = (wr * 64 + l15) * 32 + (quad ^ xsw) * 8;
    const int bfo = (wc * 64 + l15) * 32 + (quad ^ xsw) * 8;

    f32x4 acc[4][4];
    #pragma unroll
    for (int i = 0; i < 4; ++i)
        #pragma unroll
        for (int j = 0; j < 4; ++j) acc[i][j] = (f32x4){0.f, 0.f, 0.f, 0.f};

    for (int k0 = 0; k0 < Kend; k0 += 32) {
        gload_lds16(agp0 + k0, aw0);
        gload_lds16(agp1 + k0, aw1);
        gload_lds16(bgp0 + k0, bw0);
        gload_lds16(bgp1 + k0, bw1);
        __syncthreads();   // drains vmcnt: LDS tile complete

        bf16x8 af[4], bff[4];
        #pragma unroll
        for (int i = 0; i < 4; ++i) af[i] = *reinterpret_cast<const bf16x8*>(As + afo + i * 512);
        #pragma unroll
        for (int j = 0; j < 4; ++j) bff[j] = *reinterpret_cast<const bf16x8*>(Bs + bfo + j * 512);
        #pragma unroll
        for (int i = 0; i < 4; ++i)
            #pragma unroll
            for (int j = 0; j < 4; ++j)
                acc[i][j] = __builtin_amdgcn_mfma_f32_16x16x32_bf16(af[i], bff[j], acc[i][j], 0, 0, 0);

        __syncthreads();   // protect LDS before next iteration overwrites
    }

    const float* rsb = rowscale ? rowscale + (size_t)blockIdx.z * Tq : nullptr;

    // epilogue: C/D layout row=quad*4+reg, col=l15 (m89/m91-verified)
    #pragma unroll
    for (int i = 0; i < 4; ++i) {
        const int row = m0 + wr * 64 + i * 16 + quad * 4;
        #pragma unroll
        for (int j = 0; j < 4; ++j) {
            const int col = n0 + wc * 64 + j * 16 + l15;
            const float bv = bias ? bias[col] : 0.f;
            #pragma unroll
            for (int r = 0; r < 4; ++r) {
                float vv = scale * acc[i][j][r] + bv;
                if (act == 1) vv = fast_gelu(vv);
                else if (act == 2)
                    vv = (col <= row + r) ? __builtin_amdgcn_exp2f(1.4426950408889634f * vv) : 0.f;
                if (rsb) vv *= rsb[row + r];
                const size_t idx2 = (size_t)(row + r) * ldc + col + (size_t)blockIdx.z * sC;
                if (Cf) Cf[idx2] = vv;
                else    Cb[idx2] = f2b(vv);
            }
        }
    }
}

extern "C" void kernel_launch(void* const* d_in, const int* in_sizes, int n_in,
                              void* d_out, int out_size, void* d_ws, size_t ws_size,
                              hipStream_t stream)
{
    (void)in_sizes; (void)n_in; (void)out_size; (void)ws_size;
    const float* x     = (const float*)d_in[0];
    const float* ln1g  = (const float*)d_in[1];
    const float* ln1b  = (const float*)d_in[2];
    const float* Wqkv  = (const float*)d_in[3];
    const float* bqkv  = (const float*)d_in[4];
    const float* Wproj = (const float*)d_in[5];
    const float* bproj = (const float*)d_in[6];
    const float* ln2g  = (const float*)d_in[7];
    const float* ln2b  = (const float*)d_in[8];
    const float* W1    = (const float*)d_in[9];
    const float* b1    = (const float*)d_in[10];
    const float* W2    = (const float*)d_in[11];
    const float* b2    = (const float*)d_in[12];
    float* out = (float*)d_out;

    // ---- workspace arena (bf16 elements) ----
    char* ws = (char*)d_ws;
    size_t off = 0;
    auto alloc = [&](size_t elems) { bf16* p = (bf16*)(ws + off); off += elems * sizeof(bf16); return p; };
    bf16* WqkvT  = alloc(3072UL * 1024);
    bf16* WprojT = alloc(1024UL * 1024);
    bf16* W1T    = alloc(4096UL * 1024);
    bf16* W2T    = alloc(1024UL * 4096);
    bf16* h      = alloc(8192UL * 1024);        // LN1 out; later reused as `a`
    bf16* kqv    = alloc(8192UL * 3072);        // per-row k|q|v
    bf16* vT     = alloc(4UL * 1024 * 2048);
    bf16* attn   = alloc(4UL * 2048 * 2048);    // unnormalized exp'd scores
    float* invl  = (float*)alloc(8192UL * 2);   // 1/rowsum, 8192 floats
    // aliases (lifetimes disjoint):
    bf16* a   = h;
    bf16* p   = kqv;
    bf16* h2  = kqv + 8192UL * 1024;
    bf16* m   = kqv + 2UL * 8192 * 1024;        // spans kqv-tail + vT + attn

    const long T3D = (long)Tq * 3072, TT = (long)Tq * Tq, DT = (long)Dq * Tq, TD = (long)Tq * Dq;

    // weight transposes + fp32->bf16 (W[K,N] -> WT[N,K]); grid (cols/64, rows/64)
    transpose_f2b_kernel<<<dim3(48, 16), 256, 0, stream>>>(Wqkv,  WqkvT,  3072L, 1024L);
    transpose_f2b_kernel<<<dim3(16, 16), 256, 0, stream>>>(Wproj, WprojT, 1024L, 1024L);
    transpose_f2b_kernel<<<dim3(64, 16), 256, 0, stream>>>(W1,   W1T,    4096L, 1024L);
    transpose_f2b_kernel<<<dim3(16, 64), 256, 0, stream>>>(W2,   W2T,    1024L, 4096L);

    ln_kernel<float><<<8192, 256, 0, stream>>>(x, ln1g, ln1b, h);

    // kqv = h @ Wqkv + bqkv    [8192, 3072]
    gemm128<<<dim3(24, 64, 1), 256, 0, stream>>>(h, WqkvT, bqkv, nullptr, kqv, nullptr,
        1024, 1024L, 1024L, 3072L, 0L, 0L, 0L, 1.f, 0, 0, 0);

    // vT[b][d][t] = v[b][t][d]
    transpose_b2b_kernel<<<dim3(16, 32, 4), 256, 0, stream>>>(kqv + 2048, vT, 3072L, 2048L, T3D, DT);

    // P-hat = exp(q @ k^T / sqrt(T)), causal-masked, triangular grid (136 tiles/batch)
    gemm128<<<dim3(136, 1, 4), 256, 0, stream>>>(kqv + 1024, kqv, nullptr, nullptr, attn, nullptr,
        1024, 3072L, 3072L, 2048L, T3D, T3D, TT, 0.022097086912079608f, 2, 1, 0);

    // invl[t] = 1 / sum_s P-hat[t,s]
    rowsum_kernel<<<8192, 256, 0, stream>>>(attn, invl);

    // a = (P-hat @ V) * invl[row]   (K truncated to m0+128)
    gemm128<<<dim3(8, 16, 4), 256, 0, stream>>>(attn, vT, nullptr, invl, a, nullptr,
        2048, 2048L, 2048L, 1024L, TT, DT, TD, 1.f, 0, 0, 1);

    // p = a @ Wproj + bproj
    gemm128<<<dim3(8, 64, 1), 256, 0, stream>>>(a, WprojT, bproj, nullptr, p, nullptr,
        1024, 1024L, 1024L, 1024L, 0L, 0L, 0L, 1.f, 0, 0, 0);

    ln_kernel<bf16><<<8192, 256, 0, stream>>>(p, ln2g, ln2b, h2);

    // m = gelu(h2 @ W1 + b1)   [8192, 4096]
    gemm128<<<dim3(32, 64, 1), 256, 0, stream>>>(h2, W1T, b1, nullptr, m, nullptr,
        1024, 1024L, 1024L, 4096L, 0L, 0L, 0L, 1.f, 1, 0, 0);

    // out = m @ W2 + b2        [8192, 1024]  (fp32 out)
    gemm128<<<dim3(8, 64, 1), 256, 0, stream>>>(m, W2T, b2, nullptr, nullptr, out,
        4096, 4096L, 4096L, 1024L, 0L, 0L, 0L, 1.f, 0, 0, 0);
}

// Round 7
// 524.147 us; speedup vs baseline: 3.8920x; 1.0544x over previous
//
#include <hip/hip_runtime.h>
#include <hip/hip_bf16.h>

typedef __hip_bfloat16 bf16;
typedef __bf16 bf16x8 __attribute__((ext_vector_type(8)));
typedef __bf16 bf16x4 __attribute__((ext_vector_type(4)));
typedef __bf16 bf16x2 __attribute__((ext_vector_type(2)));
typedef float f32x4 __attribute__((ext_vector_type(4)));

static constexpr int Bq = 4, Tq = 2048, Dq = 1024;

__device__ inline float b2f(bf16 h) { return __bfloat162float(h); }
__device__ inline bf16 f2b(float f) { return __float2bfloat16(f); }

// async global->LDS, 16 B per lane. LDS dst = wave-uniform base + lane*16.
__device__ __forceinline__ void gload_lds16(const bf16* g, bf16* lds_wave_base) {
    __builtin_amdgcn_global_load_lds((const __attribute__((address_space(1))) void*)g,
                                     (__attribute__((address_space(3))) void*)lds_wave_base,
                                     16, 0, 0);
}

// fast tanh-approx GELU: x * sigmoid(1.5957691x + 0.0713548x^3), via exp2+rcp
__device__ __forceinline__ float fast_gelu(float x) {
    float u = x * (0.7978845608028654f + 0.03567740814183427f * x * x);
    float e = __builtin_amdgcn_exp2f(-2.885390081777927f * u);
    return x * __builtin_amdgcn_rcpf(1.f + e);
}

__device__ inline void ld4f(const float* p, float* v) {
    float4 t = *reinterpret_cast<const float4*>(p);
    v[0] = t.x; v[1] = t.y; v[2] = t.z; v[3] = t.w;
}
__device__ inline void ld4f(const bf16* p, float* v) {
    bf16x4 t = *reinterpret_cast<const bf16x4*>(p);
    v[0] = (float)t[0]; v[1] = (float)t[1]; v[2] = (float)t[2]; v[3] = (float)t[3];
}

// ---------------- LayerNorm body (one block per row, D=1024), fp32 gamma/beta ----------------
template <typename Tin>
__device__ __forceinline__ void ln_body(const Tin* __restrict__ x, const float* __restrict__ g,
                                        const float* __restrict__ b, bf16* __restrict__ out,
                                        int row, float* sred)
{
    const int tid = threadIdx.x;
    const int s0 = tid * 4;
    const Tin* xr = x + (size_t)row * Dq;
    bf16* orow = out + (size_t)row * Dq;
    float v[4], gv[4], bv[4];
    ld4f(xr + s0, v);
    ld4f(g + s0, gv);
    ld4f(b + s0, bv);
    float sum = v[0] + v[1] + v[2] + v[3];
    float sq = v[0]*v[0] + v[1]*v[1] + v[2]*v[2] + v[3]*v[3];
    for (int o = 32; o > 0; o >>= 1) { sum += __shfl_xor(sum, o); sq += __shfl_xor(sq, o); }
    const int w = tid >> 6;
    if ((tid & 63) == 0) { sred[w] = sum; sred[4 + w] = sq; }
    __syncthreads();
    const float ts = sred[0] + sred[1] + sred[2] + sred[3];
    const float tq = sred[4] + sred[5] + sred[6] + sred[7];
    const float mean = ts / Dq;
    const float rs = rsqrtf(tq / Dq - mean * mean + 1e-5f);
    bf16x4 o4;
    #pragma unroll
    for (int i = 0; i < 4; ++i) o4[i] = (__bf16)((v[i] - mean) * rs * gv[i] + bv[i]);
    *reinterpret_cast<bf16x4*>(orow + s0) = o4;
}

__global__ void ln_kernel(const bf16* __restrict__ x, const float* __restrict__ g,
                          const float* __restrict__ b, bf16* __restrict__ out)
{
    __shared__ float sred[8];
    ln_body(x, g, b, out, blockIdx.x, sred);
}

// ---------------- prep: LN1 (8192 blocks) + 4 weight transposes (3072 tile-blocks) ----------------
// transpose: 64x64 fp32->bf16 tile, coalesced read, bf16x2 write.
__global__ void prep_kernel(const float* __restrict__ x, const float* __restrict__ g,
                            const float* __restrict__ b, bf16* __restrict__ h,
                            const float* __restrict__ Wqkv, bf16* __restrict__ WqkvT,
                            const float* __restrict__ Wproj, bf16* __restrict__ WprojT,
                            const float* __restrict__ W1, bf16* __restrict__ W1T,
                            const float* __restrict__ W2, bf16* __restrict__ W2T)
{
    __shared__ float smem[64 * 65];
    int id = blockIdx.x;
    if (id < 8192) { ln_body(x, g, b, h, id, smem); return; }
    id -= 8192;
    const float* src; bf16* dst; long ldin, ldout; int gx;
    if (id < 768)       { src = Wqkv;  dst = WqkvT;  ldin = 3072; ldout = 1024; gx = 48; }
    else if (id < 1024) { id -= 768;  src = Wproj; dst = WprojT; ldin = 1024; ldout = 1024; gx = 16; }
    else if (id < 2048) { id -= 1024; src = W1;    dst = W1T;    ldin = 4096; ldout = 1024; gx = 64; }
    else                { id -= 2048; src = W2;    dst = W2T;    ldin = 1024; ldout = 4096; gx = 16; }
    const int c0 = (id % gx) * 64, r0 = (id / gx) * 64;
    const int tid = threadIdx.x;
    const int tx = tid & 63, ty = tid >> 6;
    float (*tile)[65] = reinterpret_cast<float(*)[65]>(smem);
    #pragma unroll
    for (int i = 0; i < 16; ++i) {
        int r = ty + i * 4;
        tile[r][tx] = src[(size_t)(r0 + r) * ldin + c0 + tx];
    }
    __syncthreads();
    const int px = tid & 31, cy = tid >> 5;
    #pragma unroll
    for (int i = 0; i < 8; ++i) {
        int cc = cy + i * 8;
        bf16x2 p;
        p[0] = (__bf16)tile[px * 2][cc];
        p[1] = (__bf16)tile[px * 2 + 1][cc];
        *reinterpret_cast<bf16x2*>(&dst[(size_t)(c0 + cc) * ldout + r0 + px * 2]) = p;
    }
}

// ---------------- 64x64 pair-vectorized transpose bf16 -> bf16 (for V^T) ----------------
__global__ void transpose_b2b_kernel(const bf16* __restrict__ in, bf16* __restrict__ out,
                                     long ldin, long ldout, long inBatch, long outBatch)
{
    __shared__ bf16 tile[64][66];
    const bf16* ip = in + (size_t)blockIdx.z * inBatch;
    bf16* op = out + (size_t)blockIdx.z * outBatch;
    const int c0 = blockIdx.x * 64, r0 = blockIdx.y * 64;
    const int tid = threadIdx.x;
    const int tx = tid & 31, ty = tid >> 5;
    #pragma unroll
    for (int i = 0; i < 8; ++i) {
        int r = ty + i * 8;
        *reinterpret_cast<bf16x2*>(&tile[r][tx * 2]) =
            *reinterpret_cast<const bf16x2*>(&ip[(size_t)(r0 + r) * ldin + c0 + tx * 2]);
    }
    __syncthreads();
    #pragma unroll
    for (int i = 0; i < 8; ++i) {
        int cc = ty + i * 8;
        bf16x2 p;
        p[0] = tile[tx * 2][cc];
        p[1] = tile[tx * 2 + 1][cc];
        *reinterpret_cast<bf16x2*>(&op[(size_t)(c0 + cc) * ldout + r0 + tx * 2]) = p;
    }
}

// ---------------- 128x128 LDS-staged MFMA GEMM ----------------
// C = act(scale * A @ Bt^T + bias). A:[M,K] (lda), Bt:[N,K] (ldb), bf16.
// ACT: 0 none, 1 gelu, 2 exp2 w/ causal mask. TRI: lower-triangle grid decode.
// CK: truncate K at m0+128 (attn@V: P cols > row are zero).
// FR: fused row-sum via extra all-ones-B MFMA; epilogue scales by rcp(rowsum).
//     (C/D layout of the ones-MFMA matches epilogue row indexing exactly.)
template <int ACT, int TRI, int CK, int FR>
__global__ void gemm128(const bf16* __restrict__ A, const bf16* __restrict__ Bt,
                        const float* __restrict__ bias,
                        bf16* __restrict__ Cb, float* __restrict__ Cf,
                        int K, long lda, long ldb, long ldc,
                        long sA, long sB, long sC, float scale)
{
    int bx, by;
    if (TRI) {
        const int lin = blockIdx.x;
        int t = (int)((sqrtf(8.f * lin + 1.f) - 1.f) * 0.5f);
        while ((t + 1) * (t + 2) / 2 <= lin) ++t;
        while (t * (t + 1) / 2 > lin) --t;
        by = t; bx = lin - t * (t + 1) / 2;
    } else {
        // XCD-banded remap (bijective; gy % 8 == 0 for all our grids)
        const int gx = gridDim.x, gy = gridDim.y;
        const int lin = blockIdx.x + gx * blockIdx.y;
        const int band = lin & 7;
        const int idx = lin >> 3;
        bx = idx % gx;
        by = band * (gy >> 3) + idx / gx;
    }

    const int m0 = by * 128, n0 = bx * 128;
    const int Kend = CK ? min(K, m0 + 128) : K;

    __shared__ bf16 As[128 * 32];
    __shared__ bf16 Bs[128 * 32];

    const bf16* Ab = A + (size_t)blockIdx.z * sA;
    const bf16* Bb = Bt + (size_t)blockIdx.z * sB;
    const int tid = threadIdx.x;
    const int wid = tid >> 6, lane = tid & 63;
    const int wr = wid >> 1, wc = wid & 1;
    const int l15 = lane & 15, quad = lane >> 4;

    // staging: lane's LDS slot is granule (srow, lane&3); fetches global granule
    // (lane&3) ^ ((srow>>1)&3) so data lands swizzled (bank-conflict-free frag reads).
    const int srow = wid * 16 + (lane >> 2);
    const int scol = (((lane & 3) ^ ((srow >> 1) & 3))) * 8;
    const bf16* agp0 = Ab + (size_t)(m0 + srow) * lda + scol;
    const bf16* agp1 = Ab + (size_t)(m0 + 64 + srow) * lda + scol;
    const bf16* bgp0 = Bb + (size_t)(n0 + srow) * ldb + scol;
    const bf16* bgp1 = Bb + (size_t)(n0 + 64 + srow) * ldb + scol;
    bf16* aw0 = As + wid * 512;
    bf16* aw1 = As + 2048 + wid * 512;
    bf16* bw0 = Bs + wid * 512;
    bf16* bw1 = Bs + 2048 + wid * 512;

    // fragment read offsets: swizzle xor = (l15>>1)&3 (constant across i/j)
    const int xsw = (l15 >> 1) & 3;
    const int afo = (wr * 64 + l15) * 32 + (quad ^ xsw) * 8;
    const int bfo = (wc * 64 + l15) * 32 + (quad ^ xsw) * 8;

    f32x4 acc[4][4];
    #pragma unroll
    for (int i = 0; i < 4; ++i)
        #pragma unroll
        for (int j = 0; j < 4; ++j) acc[i][j] = (f32x4){0.f, 0.f, 0.f, 0.f};

    f32x4 acc_l[4];
    bf16x8 ones;
    if (FR) {
        #pragma unroll
        for (int i = 0; i < 4; ++i) acc_l[i] = (f32x4){0.f, 0.f, 0.f, 0.f};
        #pragma unroll
        for (int i = 0; i < 8; ++i) ones[i] = (__bf16)1.0f;
    }

    for (int k0 = 0; k0 < Kend; k0 += 32) {
        gload_lds16(agp0 + k0, aw0);
        gload_lds16(agp1 + k0, aw1);
        gload_lds16(bgp0 + k0, bw0);
        gload_lds16(bgp1 + k0, bw1);
        __syncthreads();   // drains vmcnt: LDS tile complete

        bf16x8 af[4], bff[4];
        #pragma unroll
        for (int i = 0; i < 4; ++i) af[i] = *reinterpret_cast<const bf16x8*>(As + afo + i * 512);
        #pragma unroll
        for (int j = 0; j < 4; ++j) bff[j] = *reinterpret_cast<const bf16x8*>(Bs + bfo + j * 512);
        #pragma unroll
        for (int i = 0; i < 4; ++i)
            #pragma unroll
            for (int j = 0; j < 4; ++j)
                acc[i][j] = __builtin_amdgcn_mfma_f32_16x16x32_bf16(af[i], bff[j], acc[i][j], 0, 0, 0);
        if (FR) {
            #pragma unroll
            for (int i = 0; i < 4; ++i)
                acc_l[i] = __builtin_amdgcn_mfma_f32_16x16x32_bf16(af[i], ones, acc_l[i], 0, 0, 0);
        }

        __syncthreads();   // protect LDS before next iteration overwrites
    }

    // epilogue: C/D layout row=quad*4+reg, col=l15 (m89/m91-verified)
    #pragma unroll
    for (int i = 0; i < 4; ++i) {
        const int row = m0 + wr * 64 + i * 16 + quad * 4;
        #pragma unroll
        for (int j = 0; j < 4; ++j) {
            const int col = n0 + wc * 64 + j * 16 + l15;
            const float bv = bias ? bias[col] : 0.f;
            #pragma unroll
            for (int r = 0; r < 4; ++r) {
                float vv = scale * acc[i][j][r] + bv;
                if (ACT == 1) vv = fast_gelu(vv);
                else if (ACT == 2)
                    vv = (col <= row + r) ? __builtin_amdgcn_exp2f(1.4426950408889634f * vv) : 0.f;
                if (FR) vv *= __builtin_amdgcn_rcpf(acc_l[i][r]);
                const size_t idx2 = (size_t)(row + r) * ldc + col + (size_t)blockIdx.z * sC;
                if (Cf) Cf[idx2] = vv;
                else    Cb[idx2] = f2b(vv);
            }
        }
    }
}

extern "C" void kernel_launch(void* const* d_in, const int* in_sizes, int n_in,
                              void* d_out, int out_size, void* d_ws, size_t ws_size,
                              hipStream_t stream)
{
    (void)in_sizes; (void)n_in; (void)out_size; (void)ws_size;
    const float* x     = (const float*)d_in[0];
    const float* ln1g  = (const float*)d_in[1];
    const float* ln1b  = (const float*)d_in[2];
    const float* Wqkv  = (const float*)d_in[3];
    const float* bqkv  = (const float*)d_in[4];
    const float* Wproj = (const float*)d_in[5];
    const float* bproj = (const float*)d_in[6];
    const float* ln2g  = (const float*)d_in[7];
    const float* ln2b  = (const float*)d_in[8];
    const float* W1    = (const float*)d_in[9];
    const float* b1    = (const float*)d_in[10];
    const float* W2    = (const float*)d_in[11];
    const float* b2    = (const float*)d_in[12];
    float* out = (float*)d_out;

    // ---- workspace arena (bf16 elements) ----
    char* ws = (char*)d_ws;
    size_t off = 0;
    auto alloc = [&](size_t elems) { bf16* p = (bf16*)(ws + off); off += elems * sizeof(bf16); return p; };
    bf16* WqkvT  = alloc(3072UL * 1024);
    bf16* WprojT = alloc(1024UL * 1024);
    bf16* W1T    = alloc(4096UL * 1024);
    bf16* W2T    = alloc(1024UL * 4096);
    bf16* h      = alloc(8192UL * 1024);        // LN1 out; later reused as `a`
    bf16* kqv    = alloc(8192UL * 3072);        // per-row k|q|v
    bf16* vT     = alloc(4UL * 1024 * 2048);
    bf16* attn   = alloc(4UL * 2048 * 2048);    // unnormalized exp'd scores
    // aliases (lifetimes disjoint):
    bf16* a   = h;
    bf16* p   = kqv;
    bf16* h2  = kqv + 8192UL * 1024;
    bf16* m   = kqv + 2UL * 8192 * 1024;        // spans kqv-tail + vT + attn

    const long T3D = (long)Tq * 3072, TT = (long)Tq * Tq, DT = (long)Dq * Tq, TD = (long)Tq * Dq;

    // prep: LN1 + all 4 weight transposes in one dispatch
    prep_kernel<<<11264, 256, 0, stream>>>(x, ln1g, ln1b, h,
                                           Wqkv, WqkvT, Wproj, WprojT, W1, W1T, W2, W2T);

    // kqv = h @ Wqkv + bqkv    [8192, 3072]
    gemm128<0,0,0,0><<<dim3(24, 64, 1), 256, 0, stream>>>(h, WqkvT, bqkv, kqv, nullptr,
        1024, 1024L, 1024L, 3072L, 0L, 0L, 0L, 1.f);

    // vT[b][d][t] = v[b][t][d]
    transpose_b2b_kernel<<<dim3(16, 32, 4), 256, 0, stream>>>(kqv + 2048, vT, 3072L, 2048L, T3D, DT);

    // P-hat = exp(q @ k^T / sqrt(T)), causal-masked, triangular grid (136 tiles/batch)
    gemm128<2,1,0,0><<<dim3(136, 1, 4), 256, 0, stream>>>(kqv + 1024, kqv, nullptr, attn, nullptr,
        1024, 3072L, 3072L, 2048L, T3D, T3D, TT, 0.022097086912079608f);

    // a = (P-hat @ V) * rcp(rowsum)   (K truncated to m0+128; rowsum fused via ones-MFMA)
    gemm128<0,0,1,1><<<dim3(8, 16, 4), 256, 0, stream>>>(attn, vT, nullptr, a, nullptr,
        2048, 2048L, 2048L, 1024L, TT, DT, TD, 1.f);

    // p = a @ Wproj + bproj
    gemm128<0,0,0,0><<<dim3(8, 64, 1), 256, 0, stream>>>(a, WprojT, bproj, p, nullptr,
        1024, 1024L, 1024L, 1024L, 0L, 0L, 0L, 1.f);

    ln_kernel<<<8192, 256, 0, stream>>>(p, ln2g, ln2b, h2);

    // m = gelu(h2 @ W1 + b1)   [8192, 4096]
    gemm128<1,0,0,0><<<dim3(32, 64, 1), 256, 0, stream>>>(h2, W1T, b1, m, nullptr,
        1024, 1024L, 1024L, 4096L, 0L, 0L, 0L, 1.f);

    // out = m @ W2 + b2        [8192, 1024]  (fp32 out)
    gemm128<0,0,0,0><<<dim3(8, 64, 1), 256, 0, stream>>>(m, W2T, b2, nullptr, out,
        4096, 4096L, 4096L, 1024L, 0L, 0L, 0L, 1.f);
}

// Round 8
// 499.575 us; speedup vs baseline: 4.0834x; 1.0492x over previous
//
#include <hip/hip_runtime.h>
#include <hip/hip_bf16.h>

typedef __hip_bfloat16 bf16;
typedef __bf16 bf16x8 __attribute__((ext_vector_type(8)));
typedef __bf16 bf16x4 __attribute__((ext_vector_type(4)));
typedef __bf16 bf16x2 __attribute__((ext_vector_type(2)));
typedef float f32x4 __attribute__((ext_vector_type(4)));

static constexpr int Bq = 4, Tq = 2048, Dq = 1024;

__device__ inline float b2f(bf16 h) { return __bfloat162float(h); }
__device__ inline bf16 f2b(float f) { return __float2bfloat16(f); }

// async global->LDS, 16 B per lane. LDS dst = wave-uniform base + lane*16.
__device__ __forceinline__ void gload_lds16(const bf16* g, bf16* lds_wave_base) {
    __builtin_amdgcn_global_load_lds((const __attribute__((address_space(1))) void*)g,
                                     (__attribute__((address_space(3))) void*)lds_wave_base,
                                     16, 0, 0);
}

// fast tanh-approx GELU: x * sigmoid(1.5957691x + 0.0713548x^3), via exp2+rcp
__device__ __forceinline__ float fast_gelu(float x) {
    float u = x * (0.7978845608028654f + 0.03567740814183427f * x * x);
    float e = __builtin_amdgcn_exp2f(-2.885390081777927f * u);
    return x * __builtin_amdgcn_rcpf(1.f + e);
}

__device__ inline void ld4f(const float* p, float* v) {
    float4 t = *reinterpret_cast<const float4*>(p);
    v[0] = t.x; v[1] = t.y; v[2] = t.z; v[3] = t.w;
}
__device__ inline void ld4f(const bf16* p, float* v) {
    bf16x4 t = *reinterpret_cast<const bf16x4*>(p);
    v[0] = (float)t[0]; v[1] = (float)t[1]; v[2] = (float)t[2]; v[3] = (float)t[3];
}

// ---------------- LayerNorm body (one block per row, D=1024), fp32 gamma/beta ----------------
template <typename Tin>
__device__ __forceinline__ void ln_body(const Tin* __restrict__ x, const float* __restrict__ g,
                                        const float* __restrict__ b, bf16* __restrict__ out,
                                        int row, float* sred)
{
    const int tid = threadIdx.x;
    const int s0 = tid * 4;
    const Tin* xr = x + (size_t)row * Dq;
    bf16* orow = out + (size_t)row * Dq;
    float v[4], gv[4], bv[4];
    ld4f(xr + s0, v);
    ld4f(g + s0, gv);
    ld4f(b + s0, bv);
    float sum = v[0] + v[1] + v[2] + v[3];
    float sq = v[0]*v[0] + v[1]*v[1] + v[2]*v[2] + v[3]*v[3];
    for (int o = 32; o > 0; o >>= 1) { sum += __shfl_xor(sum, o); sq += __shfl_xor(sq, o); }
    const int w = tid >> 6;
    if ((tid & 63) == 0) { sred[w] = sum; sred[4 + w] = sq; }
    __syncthreads();
    const float ts = sred[0] + sred[1] + sred[2] + sred[3];
    const float tq = sred[4] + sred[5] + sred[6] + sred[7];
    const float mean = ts / Dq;
    const float rs = rsqrtf(tq / Dq - mean * mean + 1e-5f);
    bf16x4 o4;
    #pragma unroll
    for (int i = 0; i < 4; ++i) o4[i] = (__bf16)((v[i] - mean) * rs * gv[i] + bv[i]);
    *reinterpret_cast<bf16x4*>(orow + s0) = o4;
}

__global__ void ln_kernel(const bf16* __restrict__ x, const float* __restrict__ g,
                          const float* __restrict__ b, bf16* __restrict__ out)
{
    __shared__ float sred[8];
    ln_body(x, g, b, out, blockIdx.x, sred);
}

// ---------------- prep: LN1 (8192 blocks) + 4 weight transposes (3072 tile-blocks) ----------------
__global__ void prep_kernel(const float* __restrict__ x, const float* __restrict__ g,
                            const float* __restrict__ b, bf16* __restrict__ h,
                            const float* __restrict__ Wqkv, bf16* __restrict__ WqkvT,
                            const float* __restrict__ Wproj, bf16* __restrict__ WprojT,
                            const float* __restrict__ W1, bf16* __restrict__ W1T,
                            const float* __restrict__ W2, bf16* __restrict__ W2T)
{
    __shared__ float smem[64 * 65];
    int id = blockIdx.x;
    if (id < 8192) { ln_body(x, g, b, h, id, smem); return; }
    id -= 8192;
    const float* src; bf16* dst; long ldin, ldout; int gx;
    if (id < 768)       { src = Wqkv;  dst = WqkvT;  ldin = 3072; ldout = 1024; gx = 48; }
    else if (id < 1024) { id -= 768;  src = Wproj; dst = WprojT; ldin = 1024; ldout = 1024; gx = 16; }
    else if (id < 2048) { id -= 1024; src = W1;    dst = W1T;    ldin = 4096; ldout = 1024; gx = 64; }
    else                { id -= 2048; src = W2;    dst = W2T;    ldin = 1024; ldout = 4096; gx = 16; }
    const int c0 = (id % gx) * 64, r0 = (id / gx) * 64;
    const int tid = threadIdx.x;
    const int tx = tid & 63, ty = tid >> 6;
    float (*tile)[65] = reinterpret_cast<float(*)[65]>(smem);
    #pragma unroll
    for (int i = 0; i < 16; ++i) {
        int r = ty + i * 4;
        tile[r][tx] = src[(size_t)(r0 + r) * ldin + c0 + tx];
    }
    __syncthreads();
    const int px = tid & 31, cy = tid >> 5;
    #pragma unroll
    for (int i = 0; i < 8; ++i) {
        int cc = cy + i * 8;
        bf16x2 p;
        p[0] = (__bf16)tile[px * 2][cc];
        p[1] = (__bf16)tile[px * 2 + 1][cc];
        *reinterpret_cast<bf16x2*>(&dst[(size_t)(c0 + cc) * ldout + r0 + px * 2]) = p;
    }
}

// ---------------- 64x64 pair-vectorized transpose bf16 -> bf16 (for V^T) ----------------
__global__ void transpose_b2b_kernel(const bf16* __restrict__ in, bf16* __restrict__ out,
                                     long ldin, long ldout, long inBatch, long outBatch)
{
    __shared__ bf16 tile[64][66];
    const bf16* ip = in + (size_t)blockIdx.z * inBatch;
    bf16* op = out + (size_t)blockIdx.z * outBatch;
    const int c0 = blockIdx.x * 64, r0 = blockIdx.y * 64;
    const int tid = threadIdx.x;
    const int tx = tid & 31, ty = tid >> 5;
    #pragma unroll
    for (int i = 0; i < 8; ++i) {
        int r = ty + i * 8;
        *reinterpret_cast<bf16x2*>(&tile[r][tx * 2]) =
            *reinterpret_cast<const bf16x2*>(&ip[(size_t)(r0 + r) * ldin + c0 + tx * 2]);
    }
    __syncthreads();
    #pragma unroll
    for (int i = 0; i < 8; ++i) {
        int cc = ty + i * 8;
        bf16x2 p;
        p[0] = tile[tx * 2][cc];
        p[1] = tile[tx * 2 + 1][cc];
        *reinterpret_cast<bf16x2*>(&op[(size_t)(c0 + cc) * ldout + r0 + tx * 2]) = p;
    }
}

// ---------------- 128x128 LDS-staged MFMA GEMM, BK=64 ----------------
// C = act(scale * A @ Bt^T + bias). A:[M,K] (lda), Bt:[N,K] (ldb), bf16.
// ACT: 0 none, 1 gelu, 2 exp2 w/ causal mask. TRI: lower-triangle grid decode.
// CK: truncate K at m0+128 (attn@V). FR: fused row-sum via all-ones-B MFMA.
// LDS tile 128x64 (32 KB total, row stride 128 B). Swizzle: granule slot s at row r
// holds global granule s^(r&7); frag reads land 2 lanes/bank (free, m136).
// BK=64 halves the per-iteration vmcnt(0)+barrier drains vs BK=32 (the m97 stall).
template <int ACT, int TRI, int CK, int FR>
__global__ void gemm128(const bf16* __restrict__ A, const bf16* __restrict__ Bt,
                        const float* __restrict__ bias,
                        bf16* __restrict__ Cb, float* __restrict__ Cf,
                        int K, long lda, long ldb, long ldc,
                        long sA, long sB, long sC, float scale)
{
    int bx, by;
    if (TRI) {
        const int lin = blockIdx.x;
        int t = (int)((sqrtf(8.f * lin + 1.f) - 1.f) * 0.5f);
        while ((t + 1) * (t + 2) / 2 <= lin) ++t;
        while (t * (t + 1) / 2 > lin) --t;
        by = t; bx = lin - t * (t + 1) / 2;
    } else {
        // XCD-banded remap (bijective; gy % 8 == 0 for all our grids)
        const int gx = gridDim.x, gy = gridDim.y;
        const int lin = blockIdx.x + gx * blockIdx.y;
        const int band = lin & 7;
        const int idx = lin >> 3;
        bx = idx % gx;
        by = band * (gy >> 3) + idx / gx;
    }

    const int m0 = by * 128, n0 = bx * 128;
    const int Kend = CK ? min(K, m0 + 128) : K;

    __shared__ bf16 As[128 * 64];
    __shared__ bf16 Bs[128 * 64];

    const bf16* Ab = A + (size_t)blockIdx.z * sA;
    const bf16* Bb = Bt + (size_t)blockIdx.z * sB;
    const int tid = threadIdx.x;
    const int wid = tid >> 6, lane = tid & 63;
    const int wr = wid >> 1, wc = wid & 1;
    const int l15 = lane & 15, quad = lane >> 4;

    // staging: wave wid covers rows wid*32 .. wid*32+31 in 4 issues of 8 rows.
    // lane: rloc = lane>>3 (row within issue), slot = lane&7 (LDS granule col).
    // fetches global granule slot^rloc so LDS slot (r,s) holds granule s^(r&7).
    const int rloc = lane >> 3, slot = lane & 7;
    const bf16* agp = Ab + (size_t)(m0 + wid * 32 + rloc) * lda + (slot ^ rloc) * 8;
    const bf16* bgp = Bb + (size_t)(n0 + wid * 32 + rloc) * ldb + (slot ^ rloc) * 8;
    bf16* awb = As + wid * 32 * 64;
    bf16* bwb = Bs + wid * 32 * 64;

    // fragment reads: row wr*64+i*16+l15; logical granule sub*4+quad -> slot
    // (sub*4+quad)^(l15&7). sub1 offset = sub0 ^ 32 elems.
    const int afo = (wr * 64 + l15) * 64 + ((quad ^ (l15 & 7)) * 8);
    const int bfo = (wc * 64 + l15) * 64 + ((quad ^ (l15 & 7)) * 8);

    f32x4 acc[4][4];
    #pragma unroll
    for (int i = 0; i < 4; ++i)
        #pragma unroll
        for (int j = 0; j < 4; ++j) acc[i][j] = (f32x4){0.f, 0.f, 0.f, 0.f};

    f32x4 acc_l[4];
    bf16x8 ones;
    if (FR) {
        #pragma unroll
        for (int i = 0; i < 4; ++i) acc_l[i] = (f32x4){0.f, 0.f, 0.f, 0.f};
        #pragma unroll
        for (int i = 0; i < 8; ++i) ones[i] = (__bf16)1.0f;
    }

    for (int k0 = 0; k0 < Kend; k0 += 64) {
        #pragma unroll
        for (int i = 0; i < 4; ++i) {
            gload_lds16(agp + k0 + (size_t)(i * 8) * lda, awb + i * 8 * 64);
            gload_lds16(bgp + k0 + (size_t)(i * 8) * ldb, bwb + i * 8 * 64);
        }
        __syncthreads();   // drains vmcnt: LDS tile complete

        bf16x8 af0[4], bf0[4], af1[4], bf1[4];
        #pragma unroll
        for (int i = 0; i < 4; ++i) {
            af0[i] = *reinterpret_cast<const bf16x8*>(As + (afo ^ 0)  + i * 1024);
            af1[i] = *reinterpret_cast<const bf16x8*>(As + (afo ^ 32) + i * 1024);
        }
        #pragma unroll
        for (int j = 0; j < 4; ++j) {
            bf0[j] = *reinterpret_cast<const bf16x8*>(Bs + (bfo ^ 0)  + j * 1024);
            bf1[j] = *reinterpret_cast<const bf16x8*>(Bs + (bfo ^ 32) + j * 1024);
        }
        #pragma unroll
        for (int i = 0; i < 4; ++i)
            #pragma unroll
            for (int j = 0; j < 4; ++j)
                acc[i][j] = __builtin_amdgcn_mfma_f32_16x16x32_bf16(af0[i], bf0[j], acc[i][j], 0, 0, 0);
        if (FR) {
            #pragma unroll
            for (int i = 0; i < 4; ++i)
                acc_l[i] = __builtin_amdgcn_mfma_f32_16x16x32_bf16(af0[i], ones, acc_l[i], 0, 0, 0);
        }
        #pragma unroll
        for (int i = 0; i < 4; ++i)
            #pragma unroll
            for (int j = 0; j < 4; ++j)
                acc[i][j] = __builtin_amdgcn_mfma_f32_16x16x32_bf16(af1[i], bf1[j], acc[i][j], 0, 0, 0);
        if (FR) {
            #pragma unroll
            for (int i = 0; i < 4; ++i)
                acc_l[i] = __builtin_amdgcn_mfma_f32_16x16x32_bf16(af1[i], ones, acc_l[i], 0, 0, 0);
        }

        __syncthreads();   // protect LDS before next iteration overwrites
    }

    // epilogue: C/D layout row=quad*4+reg, col=l15 (m89/m91-verified)
    #pragma unroll
    for (int i = 0; i < 4; ++i) {
        const int row = m0 + wr * 64 + i * 16 + quad * 4;
        #pragma unroll
        for (int j = 0; j < 4; ++j) {
            const int col = n0 + wc * 64 + j * 16 + l15;
            const float bv = bias ? bias[col] : 0.f;
            #pragma unroll
            for (int r = 0; r < 4; ++r) {
                float vv = scale * acc[i][j][r] + bv;
                if (ACT == 1) vv = fast_gelu(vv);
                else if (ACT == 2)
                    vv = (col <= row + r) ? __builtin_amdgcn_exp2f(1.4426950408889634f * vv) : 0.f;
                if (FR) vv *= __builtin_amdgcn_rcpf(acc_l[i][r]);
                const size_t idx2 = (size_t)(row + r) * ldc + col + (size_t)blockIdx.z * sC;
                if (Cf) Cf[idx2] = vv;
                else    Cb[idx2] = f2b(vv);
            }
        }
    }
}

extern "C" void kernel_launch(void* const* d_in, const int* in_sizes, int n_in,
                              void* d_out, int out_size, void* d_ws, size_t ws_size,
                              hipStream_t stream)
{
    (void)in_sizes; (void)n_in; (void)out_size; (void)ws_size;
    const float* x     = (const float*)d_in[0];
    const float* ln1g  = (const float*)d_in[1];
    const float* ln1b  = (const float*)d_in[2];
    const float* Wqkv  = (const float*)d_in[3];
    const float* bqkv  = (const float*)d_in[4];
    const float* Wproj = (const float*)d_in[5];
    const float* bproj = (const float*)d_in[6];
    const float* ln2g  = (const float*)d_in[7];
    const float* ln2b  = (const float*)d_in[8];
    const float* W1    = (const float*)d_in[9];
    const float* b1    = (const float*)d_in[10];
    const float* W2    = (const float*)d_in[11];
    const float* b2    = (const float*)d_in[12];
    float* out = (float*)d_out;

    // ---- workspace arena (bf16 elements) ----
    char* ws = (char*)d_ws;
    size_t off = 0;
    auto alloc = [&](size_t elems) { bf16* p = (bf16*)(ws + off); off += elems * sizeof(bf16); return p; };
    bf16* WqkvT  = alloc(3072UL * 1024);
    bf16* WprojT = alloc(1024UL * 1024);
    bf16* W1T    = alloc(4096UL * 1024);
    bf16* W2T    = alloc(1024UL * 4096);
    bf16* h      = alloc(8192UL * 1024);        // LN1 out; later reused as `a`
    bf16* kqv    = alloc(8192UL * 3072);        // per-row k|q|v
    bf16* vT     = alloc(4UL * 1024 * 2048);
    bf16* attn   = alloc(4UL * 2048 * 2048);    // unnormalized exp'd scores
    // aliases (lifetimes disjoint):
    bf16* a   = h;
    bf16* p   = kqv;
    bf16* h2  = kqv + 8192UL * 1024;
    bf16* m   = kqv + 2UL * 8192 * 1024;        // spans kqv-tail + vT + attn

    const long T3D = (long)Tq * 3072, TT = (long)Tq * Tq, DT = (long)Dq * Tq, TD = (long)Tq * Dq;

    // prep: LN1 + all 4 weight transposes in one dispatch
    prep_kernel<<<11264, 256, 0, stream>>>(x, ln1g, ln1b, h,
                                           Wqkv, WqkvT, Wproj, WprojT, W1, W1T, W2, W2T);

    // kqv = h @ Wqkv + bqkv    [8192, 3072]
    gemm128<0,0,0,0><<<dim3(24, 64, 1), 256, 0, stream>>>(h, WqkvT, bqkv, kqv, nullptr,
        1024, 1024L, 1024L, 3072L, 0L, 0L, 0L, 1.f);

    // vT[b][d][t] = v[b][t][d]
    transpose_b2b_kernel<<<dim3(16, 32, 4), 256, 0, stream>>>(kqv + 2048, vT, 3072L, 2048L, T3D, DT);

    // P-hat = exp(q @ k^T / sqrt(T)), causal-masked, triangular grid (136 tiles/batch)
    gemm128<2,1,0,0><<<dim3(136, 1, 4), 256, 0, stream>>>(kqv + 1024, kqv, nullptr, attn, nullptr,
        1024, 3072L, 3072L, 2048L, T3D, T3D, TT, 0.022097086912079608f);

    // a = (P-hat @ V) * rcp(rowsum)   (K truncated to m0+128; rowsum fused via ones-MFMA)
    gemm128<0,0,1,1><<<dim3(8, 16, 4), 256, 0, stream>>>(attn, vT, nullptr, a, nullptr,
        2048, 2048L, 2048L, 1024L, TT, DT, TD, 1.f);

    // p = a @ Wproj + bproj
    gemm128<0,0,0,0><<<dim3(8, 64, 1), 256, 0, stream>>>(a, WprojT, bproj, p, nullptr,
        1024, 1024L, 1024L, 1024L, 0L, 0L, 0L, 1.f);

    ln_kernel<<<8192, 256, 0, stream>>>(p, ln2g, ln2b, h2);

    // m = gelu(h2 @ W1 + b1)   [8192, 4096]
    gemm128<1,0,0,0><<<dim3(32, 64, 1), 256, 0, stream>>>(h2, W1T, b1, m, nullptr,
        1024, 1024L, 1024L, 4096L, 0L, 0L, 0L, 1.f);

    // out = m @ W2 + b2        [8192, 1024]  (fp32 out)
    gemm128<0,0,0,0><<<dim3(8, 64, 1), 256, 0, stream>>>(m, W2T, b2, nullptr, out,
        4096, 4096L, 4096L, 1024L, 0L, 0L, 0L, 1.f);
}